// Round 4
// baseline (420.513 us; speedup 1.0000x reference)
//
#include <hip/hip_runtime.h>

typedef unsigned short ushort;
typedef __attribute__((ext_vector_type(8))) short short8;
typedef __attribute__((ext_vector_type(8))) unsigned short ushort8;
typedef __attribute__((ext_vector_type(4))) unsigned short ushort4v;
typedef __attribute__((ext_vector_type(4))) float fx4;

#define MAXNNZ (256*7)

__device__ __forceinline__ ushort f2bf(float f) {
    union { float f; unsigned u; } v; v.f = f;
    unsigned r = v.u + 0x7fffu + ((v.u >> 16) & 1u);
    return (ushort)(r >> 16);
}

__device__ __forceinline__ float bf2f(ushort b) {
    union { unsigned u; float f; } v; v.u = ((unsigned)b) << 16;
    return v.f;
}

// async global->LDS, 16B per lane; LDS dest = wave-uniform base + lane*16
__device__ __forceinline__ void gload_lds16(const ushort* g, ushort* l) {
    __builtin_amdgcn_global_load_lds(
        (const __attribute__((address_space(1))) unsigned int*)g,
        (__attribute__((address_space(3))) unsigned int*)l, 16, 0, 0);
}

// ---------------- top-7 per row of coeff (rows 0..255), emit COO for cols<256 -----
__global__ __launch_bounds__(256)
void topk_kernel(const float* __restrict__ coeff,
                 int* __restrict__ coo_cnt, int* __restrict__ coo_m,
                 int* __restrict__ coo_p, float* __restrict__ coo_v)
{
    int row = blockIdx.x;            // = m index, 0..255
    int tid = threadIdx.x;
    const float* crow = coeff + (long)row * 2048;
    float av[8];
#pragma unroll
    for (int i = 0; i < 8; ++i) av[i] = fabsf(crow[tid + 256 * i]);
    __shared__ unsigned long long red[256];
    for (int t = 0; t < 7; ++t) {
        float mx = -1.f; int mi = 0;
#pragma unroll
        for (int i = 0; i < 8; ++i) if (av[i] > mx) { mx = av[i]; mi = i; }
        unsigned col = (unsigned)(tid + 256 * mi);
        unsigned long long pk = ((unsigned long long)__float_as_uint(mx) << 32)
                              | (unsigned long long)(2048u - col); // tie -> smaller col
        red[tid] = pk; __syncthreads();
        for (int s = 128; s > 0; s >>= 1) {
            if (tid < s) { if (red[tid + s] > red[tid]) red[tid] = red[tid + s]; }
            __syncthreads();
        }
        unsigned long long w = red[0];
        __syncthreads();
        unsigned wcol = 2048u - (unsigned)(w & 0xffffffffu);
        if ((wcol & 255u) == (unsigned)tid) av[wcol >> 8] = -1.f; // consume
        if (tid == 0 && wcol < 256u) {
            int pos = atomicAdd(coo_cnt, 1);
            coo_m[pos] = row; coo_p[pos] = (int)wcol; coo_v[pos] = crow[wcol];
        }
    }
}

// ---------------- COO -> CSC (single block) ----------------
__global__ __launch_bounds__(256)
void csc_kernel(const int* __restrict__ coo_cnt, const int* __restrict__ coo_m,
                const int* __restrict__ coo_p, const float* __restrict__ coo_v,
                int* __restrict__ csc_ptr, int* __restrict__ csc_m, float* __restrict__ csc_v)
{
    __shared__ int cnt[256];
    __shared__ int off[257];
    __shared__ int cur[256];
    int tid = threadIdx.x;
    cnt[tid] = 0;
    __syncthreads();
    int n = *coo_cnt; if (n > MAXNNZ) n = MAXNNZ;
    for (int e = tid; e < n; e += 256) atomicAdd(&cnt[coo_p[e]], 1);
    __syncthreads();
    if (tid == 0) {
        int s = 0;
        for (int p = 0; p < 256; ++p) { off[p] = s; s += cnt[p]; }
        off[256] = s;
    }
    __syncthreads();
    csc_ptr[tid] = off[tid];
    if (tid == 0) csc_ptr[256] = off[256];
    cur[tid] = off[tid];
    __syncthreads();
    for (int e = tid; e < n; e += 256) {
        int p = coo_p[e];
        int pos = atomicAdd(&cur[p], 1);
        csc_m[pos] = coo_m[e];
        csc_v[pos] = coo_v[e];
    }
}

// ---------------- fp32 -> bf16 convert, 4 tensors in one launch ----------------
__global__ void cvt4_kernel(const float* a0, ushort* d0, int n0,
                            const float* a1, ushort* d1, int n1,
                            const float* a2, ushort* d2, int n2,
                            const float* a3, ushort* d3, int n3)
{
    const float* s; ushort* d; int n;
    switch (blockIdx.y) {
        case 0: s = a0; d = d0; n = n0; break;
        case 1: s = a1; d = d1; n = n1; break;
        case 2: s = a2; d = d2; n = n2; break;
        default: s = a3; d = d3; n = n3; break;
    }
    int nv = n >> 2;
    for (int i = blockIdx.x * blockDim.x + threadIdx.x; i < nv; i += gridDim.x * blockDim.x) {
        fx4 v = ((const fx4*)s)[i];
        ushort4v o;
        o[0] = f2bf(v[0]); o[1] = f2bf(v[1]); o[2] = f2bf(v[2]); o[3] = f2bf(v[3]);
        ((ushort4v*)d)[i] = o;
    }
}

// ---------------- transpose f32 [z][R][C] -> bf16 [z][C][R] ----------------
__global__ __launch_bounds__(256)
void transpose_f32_bf16(const float* __restrict__ in, ushort* __restrict__ out, int R, int C)
{
    int z = blockIdx.z;
    const float* ib = in + (long)z * R * C;
    ushort* ob = out + (long)z * R * C;
    __shared__ ushort tile[64][72];
    int r0 = blockIdx.x * 64, c0 = blockIdx.y * 64;
    int tid = threadIdx.x;
    int rl = tid >> 2, sg = tid & 3;
#pragma unroll
    for (int h = 0; h < 4; ++h) {
        fx4 v = *(const fx4*)(ib + (long)(r0 + rl) * C + c0 + h * 16 + sg * 4);
#pragma unroll
        for (int i = 0; i < 4; ++i) tile[h * 16 + sg * 4 + i][rl] = f2bf(v[i]);
    }
    __syncthreads();
    int cl = rl;
#pragma unroll
    for (int h = 0; h < 2; ++h) {
        ushort8 vv = *(const ushort8*)(&tile[cl][h * 32 + sg * 8]);
        *(ushort8*)(ob + (long)(c0 + cl) * R + r0 + h * 32 + sg * 8) = vv;
    }
}

// ---------------- K-combine: ktc[z][p][d] = sum_e csc_v[e] * kbT[z][m_e][d] --------
__global__ __launch_bounds__(256)
void kcomb_kernel(const ushort* __restrict__ kbT, ushort* __restrict__ ktc,
                  const int* __restrict__ csc_ptr, const int* __restrict__ csc_m,
                  const float* __restrict__ csc_v)
{
    int z = blockIdx.y;
    int tid = threadIdx.x;
    int p = blockIdx.x * 64 + (tid >> 2);
    int d0 = (tid & 3) * 64;
    const ushort* src = kbT + (long)z * 65536;
    float acc[64];
#pragma unroll
    for (int i = 0; i < 64; ++i) acc[i] = 0.f;
    int e0 = csc_ptr[p], e1 = csc_ptr[p + 1];
    for (int e = e0; e < e1; ++e) {
        const ushort* row = src + csc_m[e] * 256 + d0;
        float c = csc_v[e];
#pragma unroll
        for (int u = 0; u < 8; ++u) {
            ushort8 v = *(const ushort8*)(row + u * 8);
#pragma unroll
            for (int t = 0; t < 8; ++t) acc[u * 8 + t] += bf2f(v[t]) * c;
        }
    }
    ushort* dst = ktc + (long)z * 65536 + (long)p * 256 + d0;
#pragma unroll
    for (int u = 0; u < 8; ++u) {
        ushort8 o;
#pragma unroll
        for (int t = 0; t < 8; ++t) o[t] = f2bf(acc[u * 8 + t]);
        *(ushort8*)(dst + u * 8) = o;
    }
}

// ---------------- fused attention: T=QK~^T/s, softmax, O = P V^T ----------------
// One block per z=(b,h), 512 threads, 2 n-halves of 128 rows.
// PQ (64 KB) holds: staged Q-half -> P (post-softmax) -> O retile. KV (2x32 KB)
// ring shared by K chunks (phase 1) and V chunks (phase 2), BK=64, stage t+1
// issued right after the phase barrier (readers of target buf finished a barrier
// ago; consumed after next vmcnt(0)). No vmcnt(0) without ~1 phase of pre-issue.
__global__ __launch_bounds__(512)
void attn_kernel(const ushort* __restrict__ Q, const ushort* __restrict__ Kt,
                 const ushort* __restrict__ V, ushort* __restrict__ O,
                 const float* __restrict__ scale_src)
{
    __shared__ __align__(16) ushort PQ[32768];      // 64 KB
    __shared__ __align__(16) ushort KV[2][16384];   // 64 KB
    __shared__ float rmax[4][128];
    __shared__ float rsum[4][128];

    int z = blockIdx.x;              // b*8 + h
    int b = z >> 3, h = z & 7;
    const ushort* Qz = Q + (long)z * 65536;            // [n][d]
    const ushort* Kz = Kt + (long)z * 65536;           // [p][d]
    const ushort* Vz = V + (long)b * 524288 + (long)h * 65536;  // [d][p]
    ushort* Ob = O + (long)b * 524288 + (long)h * 256; // [n][2048] slab, cols h*256+d

    int tid = threadIdx.x;
    int wave = tid >> 6, lane = tid & 63;
    int l16 = lane & 15, quad = lane >> 4;
    int wrow = wave >> 2, wcol = wave & 3;             // 2 x 4 wave grid
    int key = l16 & 7;

    // staging sources (pre-swizzled cols; linear dest slot = g*512 + tid):
    // K/V chunks [256 rows][64 cols]: row=slot>>3, phys chunk=slot&7, key=(row&7)
    const ushort* ksrc = Kz + (long)(tid >> 3) * 256 + (((tid & 7) ^ ((tid >> 3) & 7)) * 8);
    const ushort* vsrc = Vz + (long)(tid >> 3) * 256 + (((tid & 7) ^ ((tid >> 3) & 7)) * 8);
    // Q half [128 rows][256 cols]: row=slot>>5, phys chunk=slot&31, key=(row&7)
    const ushort* qsrc = Qz + (long)(tid >> 5) * 256 + (((tid & 31) ^ ((tid >> 5) & 7)) * 8);
    int dstoff = wave * 512;

    float sc = 1.0f / scale_src[0];

    for (int hf = 0; hf < 2; ++hf) {
        // -------- prologue: stage Q half (8 loads) + K chunk 0 (4 loads) --------
#pragma unroll
        for (int g = 0; g < 8; ++g)
            gload_lds16(qsrc + hf * 32768 + g * 4096, PQ + g * 4096 + dstoff);
#pragma unroll
        for (int g = 0; g < 4; ++g)
            gload_lds16(ksrc + (long)g * 16384, KV[0] + g * 4096 + dstoff);

        // -------- phase 1: T[128 n][256 p] = Q K~^T --------
        fx4 acc[4][4];
#pragma unroll
        for (int i = 0; i < 4; ++i)
#pragma unroll
            for (int j = 0; j < 4; ++j) acc[i][j] = (fx4){0.f, 0.f, 0.f, 0.f};

        for (int t = 0; t < 4; ++t) {
            asm volatile("s_waitcnt vmcnt(0)" ::: "memory");
            __builtin_amdgcn_s_barrier();
            if (t < 3) {
#pragma unroll
                for (int g = 0; g < 4; ++g)
                    gload_lds16(ksrc + (long)g * 16384 + (t + 1) * 64,
                                KV[(t + 1) & 1] + g * 4096 + dstoff);
            }
            const ushort* kb = KV[t & 1];
            short8 af[8], bf[8];
#pragma unroll
            for (int ks = 0; ks < 2; ++ks) {
#pragma unroll
                for (int i = 0; i < 4; ++i)
                    af[ks * 4 + i] = *(const short8*)(PQ + (wrow * 64 + i * 16 + l16) * 256
                                     + ((((t * 2 + ks) * 4 + quad) ^ key) * 8));
#pragma unroll
                for (int j = 0; j < 4; ++j)
                    bf[ks * 4 + j] = *(const short8*)(kb + (wcol * 64 + j * 16 + l16) * 64
                                     + (((ks * 4 + quad) ^ key) * 8));
            }
            asm volatile("s_waitcnt lgkmcnt(0)" ::: "memory");
            __builtin_amdgcn_sched_barrier(0);
            __builtin_amdgcn_s_setprio(1);
#pragma unroll
            for (int ks = 0; ks < 2; ++ks)
#pragma unroll
                for (int i = 0; i < 4; ++i)
#pragma unroll
                    for (int j = 0; j < 4; ++j)
                        acc[i][j] = __builtin_amdgcn_mfma_f32_16x16x32_bf16(
                            af[ks * 4 + i], bf[ks * 4 + j], acc[i][j], 0, 0, 0);
            __builtin_amdgcn_s_setprio(0);
        }

        // -------- softmax --------
#pragma unroll
        for (int i = 0; i < 4; ++i)
#pragma unroll
            for (int j = 0; j < 4; ++j)
#pragma unroll
                for (int r = 0; r < 4; ++r) acc[i][j][r] *= sc;

        float lm[4][4];
#pragma unroll
        for (int i = 0; i < 4; ++i)
#pragma unroll
            for (int r = 0; r < 4; ++r) {
                float m = -1e30f;
#pragma unroll
                for (int j = 0; j < 4; ++j) m = fmaxf(m, acc[i][j][r]);
                lm[i][r] = m;
            }
#pragma unroll
        for (int d = 1; d < 16; d <<= 1)
#pragma unroll
            for (int i = 0; i < 4; ++i)
#pragma unroll
                for (int r = 0; r < 4; ++r) lm[i][r] = fmaxf(lm[i][r], __shfl_xor(lm[i][r], d, 16));
        if (l16 == 0) {
#pragma unroll
            for (int i = 0; i < 4; ++i)
#pragma unroll
                for (int r = 0; r < 4; ++r)
                    rmax[wcol][wrow * 64 + i * 16 + quad * 4 + r] = lm[i][r];
        }
        asm volatile("s_waitcnt lgkmcnt(0)" ::: "memory");
        __builtin_amdgcn_s_barrier();

        float ls[4][4];
#pragma unroll
        for (int i = 0; i < 4; ++i)
#pragma unroll
            for (int r = 0; r < 4; ++r) {
                int row = wrow * 64 + i * 16 + quad * 4 + r;
                float M = fmaxf(fmaxf(rmax[0][row], rmax[1][row]),
                                fmaxf(rmax[2][row], rmax[3][row]));
                float s = 0.f;
#pragma unroll
                for (int j = 0; j < 4; ++j) {
                    float e = __expf(acc[i][j][r] - M);
                    acc[i][j][r] = e;
                    s += e;
                }
                ls[i][r] = s;
            }
#pragma unroll
        for (int d = 1; d < 16; d <<= 1)
#pragma unroll
            for (int i = 0; i < 4; ++i)
#pragma unroll
                for (int r = 0; r < 4; ++r) ls[i][r] += __shfl_xor(ls[i][r], d, 16);
        if (l16 == 0) {
#pragma unroll
            for (int i = 0; i < 4; ++i)
#pragma unroll
                for (int r = 0; r < 4; ++r)
                    rsum[wcol][wrow * 64 + i * 16 + quad * 4 + r] = ls[i][r];
        }
        asm volatile("s_waitcnt lgkmcnt(0)" ::: "memory");
        __builtin_amdgcn_s_barrier();

        // prefetch V chunk 0 (KV[0] dead: K2 consumed); lands under normalize
#pragma unroll
        for (int g = 0; g < 4; ++g)
            gload_lds16(vsrc + (long)g * 16384, KV[0] + g * 4096 + dstoff);

        // normalize + write P into PQ (Q dead), swizzled chunk ^= row&7
#pragma unroll
        for (int i = 0; i < 4; ++i)
#pragma unroll
            for (int r = 0; r < 4; ++r) {
                int row = wrow * 64 + i * 16 + quad * 4 + r;
                float inv = 1.0f / (rsum[0][row] + rsum[1][row] + rsum[2][row] + rsum[3][row]);
                int k2 = row & 7;
#pragma unroll
                for (int j = 0; j < 4; ++j) {
                    int p = wcol * 64 + j * 16 + l16;
                    PQ[row * 256 + ((((p >> 3) ^ k2) << 3) | (p & 7))] = f2bf(acc[i][j][r] * inv);
                }
            }
        asm volatile("s_waitcnt lgkmcnt(0)" ::: "memory");

        // -------- phase 2: O[128 n][256 d] = P V^T --------
        fx4 acc2[4][4];
#pragma unroll
        for (int i = 0; i < 4; ++i)
#pragma unroll
            for (int j = 0; j < 4; ++j) acc2[i][j] = (fx4){0.f, 0.f, 0.f, 0.f};

        for (int kk = 0; kk < 4; ++kk) {
            asm volatile("s_waitcnt vmcnt(0)" ::: "memory");
            __builtin_amdgcn_s_barrier();
            if (kk < 3) {
#pragma unroll
                for (int g = 0; g < 4; ++g)
                    gload_lds16(vsrc + (long)g * 16384 + (kk + 1) * 64,
                                KV[(kk + 1) & 1] + g * 4096 + dstoff);
            }
            const ushort* vbuf = KV[kk & 1];
            short8 pa[8], vf[8];
#pragma unroll
            for (int ks = 0; ks < 2; ++ks) {
#pragma unroll
                for (int i = 0; i < 4; ++i)
                    pa[ks * 4 + i] = *(const short8*)(PQ + (wrow * 64 + i * 16 + l16) * 256
                                     + ((((kk * 2 + ks) * 4 + quad) ^ key) * 8));
#pragma unroll
                for (int j = 0; j < 4; ++j)
                    vf[ks * 4 + j] = *(const short8*)(vbuf + (wcol * 64 + j * 16 + l16) * 64
                                     + (((ks * 4 + quad) ^ key) * 8));
            }
            asm volatile("s_waitcnt lgkmcnt(0)" ::: "memory");
            __builtin_amdgcn_sched_barrier(0);
            __builtin_amdgcn_s_setprio(1);
#pragma unroll
            for (int ks = 0; ks < 2; ++ks)
#pragma unroll
                for (int i = 0; i < 4; ++i)
#pragma unroll
                    for (int j = 0; j < 4; ++j)
                        acc2[i][j] = __builtin_amdgcn_mfma_f32_16x16x32_bf16(
                            pa[ks * 4 + i], vf[ks * 4 + j], acc2[i][j], 0, 0, 0);
            __builtin_amdgcn_s_setprio(0);
        }

        // -------- epilogue: retile O through PQ (dead), coalesced 512B rows ------
        __builtin_amdgcn_s_barrier();
#pragma unroll
        for (int i = 0; i < 4; ++i)
#pragma unroll
            for (int j = 0; j < 4; ++j) {
                int rowb = wrow * 64 + i * 16 + quad * 4;
                int col = wcol * 64 + j * 16 + l16;
#pragma unroll
                for (int rr = 0; rr < 4; ++rr) {
                    int row = rowb + rr;
                    PQ[row * 256 + ((((col >> 3) ^ (row & 7)) << 3) | (col & 7))]
                        = f2bf(acc2[i][j][rr]);
                }
            }
        asm volatile("s_waitcnt lgkmcnt(0)" ::: "memory");
        __builtin_amdgcn_s_barrier();
#pragma unroll
        for (int pass = 0; pass < 8; ++pass) {
            int row = pass * 16 + (tid >> 5), ch = tid & 31;
            ushort8 vv = *(const ushort8*)(PQ + row * 256 + ((ch ^ (row & 7)) << 3));
            *(ushort8*)(Ob + (long)(hf * 128 + row) * 2048 + ch * 8) = vv;
        }
        asm volatile("s_waitcnt lgkmcnt(0)" ::: "memory");
        __builtin_amdgcn_s_barrier();
    }
}

// ---------------- 256x256-tile NT GEMM, 8 waves, fine-phase pipelined --------------
// 4-deep LDS ring (BK=32), 2 phases per K-tile; counted vmcnt; swizzled LDS.
// MODE 4: merged QKV, A=[6144][512] wqkv, B=[8192][512] xT; sec = m0>>11 uniform.
// MODE 5: final: A=[2048][2048] wob, B=[8192][2048] obT; f32 out + bias (direct).
template<int MODE>
__global__ __launch_bounds__(512, 2)
void gemm256(const ushort* __restrict__ A, const ushort* __restrict__ B,
             void* __restrict__ C,
             const float* __restrict__ bias0, const float* __restrict__ bias1,
             const float* __restrict__ bias2,
             int MT, int K)
{
    __shared__ __align__(16) ushort lds[4][2][8192];   // 128 KiB ring: 4 x (A,B) x 256x32

    int nwg = gridDim.x;
    int bid = blockIdx.x;
    int cpx = nwg >> 3;                        // nwg % 8 == 0 guaranteed by launch
    int swz = (bid & 7) * cpx + (bid >> 3);    // XCD-aware swizzle (bijective)
    int mt = swz % MT, nt = swz / MT;
    int m0 = mt << 8, n0 = nt << 8;

    int tid = threadIdx.x;
    int wave = tid >> 6, lane = tid & 63;
    int wr = wave >> 2, wc = wave & 3;         // 2x4 wave grid; per-wave C = 128x64
    int l16 = lane & 15, quad = lane >> 4;

    int lc = (((lane & 3) ^ ((lane >> 3) & 3))) * 8;
    const ushort* gA0 = A + (long long)(m0 + wave * 16 + (lane >> 2)) * K + lc;
    const ushort* gA1 = gA0 + (long long)128 * K;
    const ushort* gB0 = B + (long long)(n0 + wave * 16 + (lane >> 2)) * K + lc;
    const ushort* gB1 = gB0 + (long long)128 * K;
    int ldso = wave * 512;                     // wave's 1KB stripe (ushorts)

    int rsw = ((l16 >> 1) & 3) * 8;
    int aoff = (wr * 128 + l16) * 32 + ((quad * 8) ^ rsw);
    int boff = (wc * 64 + l16) * 32 + ((quad * 8) ^ rsw);

    fx4 acc[8][4];
#pragma unroll
    for (int i = 0; i < 8; ++i)
#pragma unroll
        for (int j = 0; j < 4; ++j) acc[i][j] = (fx4){0.f, 0.f, 0.f, 0.f};

    auto stageA = [&](int b, int kc) {
        gload_lds16(gA0 + kc, &lds[b][0][ldso]);
        gload_lds16(gA1 + kc, &lds[b][0][4096 + ldso]);
    };
    auto stageB = [&](int b, int kc) {
        gload_lds16(gB0 + kc, &lds[b][1][ldso]);
        gload_lds16(gB1 + kc, &lds[b][1][4096 + ldso]);
    };

    short8 af[4], bf[4];
    auto readA = [&](int b, int half) {
        const ushort* p = &lds[b][0][aoff + half * 2048];
#pragma unroll
        for (int i = 0; i < 4; ++i) af[i] = *(const short8*)(p + i * 512);
    };
    auto readB = [&](int b) {
        const ushort* p = &lds[b][1][boff];
#pragma unroll
        for (int j = 0; j < 4; ++j) bf[j] = *(const short8*)(p + j * 512);
    };
    auto mma = [&](int half) {
        __builtin_amdgcn_s_setprio(1);
#pragma unroll
        for (int i = 0; i < 4; ++i)
#pragma unroll
            for (int j = 0; j < 4; ++j)
                acc[half * 4 + i][j] =
                    __builtin_amdgcn_mfma_f32_16x16x32_bf16(af[i], bf[j], acc[half * 4 + i][j], 0, 0, 0);
        __builtin_amdgcn_s_setprio(0);
    };

    int NT = K >> 5;
    stageA(0, 0);  stageB(0, 0);
    stageA(1, 32); stageB(1, 32);
    stageA(2, 64); stageB(2, 64);
    asm volatile("s_waitcnt vmcnt(8)" ::: "memory");
    __builtin_amdgcn_s_barrier();

    for (int t = 0; t < NT; ++t) {
        int b = t & 3;
        readA(b, 0); readB(b);
        if (t + 3 < NT) stageA((t + 3) & 3, (t + 3) << 5);
        __builtin_amdgcn_s_barrier();
        asm volatile("s_waitcnt lgkmcnt(0)" ::: "memory");
        __builtin_amdgcn_sched_barrier(0);
        mma(0);
        __builtin_amdgcn_s_barrier();
        readA(b, 1);
        if (t + 3 < NT) {
            stageB((t + 3) & 3, (t + 3) << 5);
            asm volatile("s_waitcnt vmcnt(8)" ::: "memory");
        } else if (t + 2 < NT) {
            asm volatile("s_waitcnt vmcnt(4)" ::: "memory");
        } else if (t + 1 < NT) {
            asm volatile("s_waitcnt vmcnt(0)" ::: "memory");
        }
        __builtin_amdgcn_s_barrier();
        asm volatile("s_waitcnt lgkmcnt(0)" ::: "memory");
        __builtin_amdgcn_sched_barrier(0);
        mma(1);
        __builtin_amdgcn_s_barrier();
    }

    if (MODE == 5) {
        float* Cf = (float*)C + (long long)nt * 524288;
#pragma unroll
        for (int i = 0; i < 8; ++i) {
            int m = m0 + wr * 128 + i * 16 + quad * 4;
#pragma unroll
            for (int j = 0; j < 4; ++j) {
                int n = wc * 64 + j * 16 + l16;
                float* dst = Cf + (long long)m * 256 + n;
#pragma unroll
                for (int r = 0; r < 4; ++r)
                    dst[(long)r * 256] = acc[i][j][r] + bias0[m + r];
            }
        }
        return;
    }

    if (MODE == 4) {
        int sec = m0 >> 11;
        int ms0 = m0 & 2047;
        ushort* ct = &lds[0][0][0];            // re-tile buffer: 128 x 264 ushorts
        if (sec < 2) {
            const float* bs = (sec == 0) ? bias0 : bias1;
            ushort* base = (ushort*)C + (long long)sec * 16777216
                         + (long long)nt * 524288 + (long long)(ms0 >> 8) * 65536;
#pragma unroll
            for (int hh = 0; hh < 2; ++hh) {
                if ((wc >> 1) == hh) {
#pragma unroll
                    for (int i = 0; i < 8; ++i)
#pragma unroll
                        for (int j = 0; j < 4; ++j) {
                            int nl = (wc & 1) * 64 + j * 16 + l16;
                            int ml = wr * 128 + i * 16 + quad * 4;
                            ushort4v pk;
#pragma unroll
                            for (int r = 0; r < 4; ++r)
                                pk[r] = f2bf(acc[i][j][r] + bs[ms0 + ml + r]);
                            *(ushort4v*)(ct + nl * 264 + ml) = pk;
                        }
                }
                __syncthreads();
                int row = tid & 127, c0 = (tid >> 7) * 64;
                ushort* dst = base + (long long)(hh * 128 + row) * 256 + c0;
                const ushort* src = ct + row * 264 + c0;
#pragma unroll
                for (int u = 0; u < 8; ++u)
                    *(ushort8*)(dst + u * 8) = *(const ushort8*)(src + u * 8);
                __syncthreads();
            }
        } else {
            ushort* base = (ushort*)C + 33554432LL + (long long)nt * 524288
                         + (long long)ms0 * 256;
#pragma unroll
            for (int hh = 0; hh < 2; ++hh) {
                if (wr == hh) {
#pragma unroll
                    for (int i = 0; i < 8; ++i)
#pragma unroll
                        for (int j = 0; j < 4; ++j) {
                            int nl = wc * 64 + j * 16 + l16;
                            int ml = i * 16 + quad * 4;
#pragma unroll
                            for (int r = 0; r < 4; ++r)
                                ct[(ml + r) * 264 + nl] =
                                    f2bf(acc[i][j][r] + bias2[ms0 + hh * 128 + ml + r]);
                        }
                }
                __syncthreads();
                int row = tid & 127, c0 = (tid >> 7) * 64;
                ushort* dst = base + (long long)(hh * 128 + row) * 256 + c0;
                const ushort* src = ct + row * 264 + c0;
#pragma unroll
                for (int u = 0; u < 8; ++u)
                    *(ushort8*)(dst + u * 8) = *(const ushort8*)(src + u * 8);
                __syncthreads();
            }
        }
        return;
    }
}

extern "C" void kernel_launch(void* const* d_in, const int* in_sizes, int n_in,
                              void* d_out, int out_size, void* d_ws, size_t ws_size,
                              hipStream_t stream)
{
    const float* x     = (const float*)d_in[0];
    const float* Wq    = (const float*)d_in[1];
    const float* bq    = (const float*)d_in[2];
    const float* Wk    = (const float*)d_in[3];
    const float* bk    = (const float*)d_in[4];
    const float* Wv    = (const float*)d_in[5];
    const float* bv    = (const float*)d_in[6];
    const float* Wo    = (const float*)d_in[7];
    const float* bo    = (const float*)d_in[8];
    const float* coeff = (const float*)d_in[9];
    const float* scale = (const float*)d_in[10];
    float* out = (float*)d_out;

    size_t o = 0;
    char* w = (char*)d_ws;
    auto take = [&](size_t bytes) -> void* {
        void* p = w + o; o += (bytes + 255) & ~(size_t)255; return p;
    };
    int*    coo_cnt = (int*)take(4);
    int*    coo_m   = (int*)take(MAXNNZ * 4);
    int*    coo_p   = (int*)take(MAXNNZ * 4);
    float*  coo_v   = (float*)take(MAXNNZ * 4);
    int*    csc_ptr = (int*)take(257 * 4);
    int*    csc_m   = (int*)take(MAXNNZ * 4);
    float*  csc_v   = (float*)take(MAXNNZ * 4);
    ushort* wqkv = (ushort*)take(6144L * 512 * 2);       // [wq;wk;wv] stacked
    ushort* wob  = (ushort*)take(2048L * 2048 * 2);
    ushort* xT   = (ushort*)take(32L * 256 * 512 * 2);   // [b][n][cin] == [8192][512]
    ushort* qkv  = (ushort*)take(3 * 16777216L * 2);     // qbT | kbT | vb contiguous
    ushort* qbT = qkv;                                   // [b][h][n][d]
    ushort* kbT = qkv + 16777216L;                       // [b][h][m][d]
    ushort* vb  = qkv + 33554432L;                       // [b][2048][256]
    ushort* ktc = (ushort*)take(16777216L * 2);          // [z][p][d]
    // alias: kbT dead after kcomb -> obT lives there (disjoint from qbT/vb/ktc reads)
    ushort* obT  = kbT;                                  // [8192][2048]
    (void)in_sizes; (void)n_in; (void)out_size; (void)ws_size;

    // 1) sparsity structure
    hipMemsetAsync(coo_cnt, 0, 4, stream);
    topk_kernel<<<256, 256, 0, stream>>>(coeff, coo_cnt, coo_m, coo_p, coo_v);
    csc_kernel<<<1, 256, 0, stream>>>(coo_cnt, coo_m, coo_p, coo_v, csc_ptr, csc_m, csc_v);

    // 2) weight converts + x transpose
    cvt4_kernel<<<dim3(1024, 4, 1), 256, 0, stream>>>(
        Wq, wqkv, 2048 * 512, Wk, wqkv + 2048L * 512, 2048 * 512,
        Wv, wqkv + 4096L * 512, 2048 * 512, Wo, wob, 2048 * 2048);
    transpose_f32_bf16<<<dim3(8, 4, 32), 256, 0, stream>>>(x, xT, 512, 256);

    // 3) merged QKV projection: [6144,512] x [8192,512]^T, 256^2 pipelined tiles
    gemm256<4><<<dim3(768, 1, 1), dim3(512, 1, 1), 0, stream>>>(
        wqkv, xT, qkv, bq, bk, bv, 24, 512);

    // 4) K-combine with sparse coeff: ktc[z][p][d]
    kcomb_kernel<<<dim3(4, 256), 256, 0, stream>>>(kbT, ktc, csc_ptr, csc_m, csc_v);

    // 5+6) fused attention: softmax(Q^T K~ / s) V -> obT [8192][2048]
    attn_kernel<<<256, 512, 0, stream>>>(qbT, ktc, vb, obT, scale);

    // 7) merged final projection: [2048,2048] x [8192,2048]^T -> out f32 [b][2048][256]
    gemm256<5><<<dim3(256, 1, 1), dim3(512, 1, 1), 0, stream>>>(
        wob, obT, out, bo, nullptr, nullptr, 8, 2048);
}

// Round 6
// 381.070 us; speedup vs baseline: 1.1035x; 1.1035x over previous
//
#include <hip/hip_runtime.h>

typedef unsigned short ushort;
typedef __attribute__((ext_vector_type(8))) short short8;
typedef __attribute__((ext_vector_type(8))) unsigned short ushort8;
typedef __attribute__((ext_vector_type(4))) unsigned short ushort4v;
typedef __attribute__((ext_vector_type(4))) float fx4;

#define MAXNNZ (256*7)

__device__ __forceinline__ ushort f2bf(float f) {
    union { float f; unsigned u; } v; v.f = f;
    unsigned r = v.u + 0x7fffu + ((v.u >> 16) & 1u);
    return (ushort)(r >> 16);
}

__device__ __forceinline__ float bf2f(ushort b) {
    union { unsigned u; float f; } v; v.u = ((unsigned)b) << 16;
    return v.f;
}

// async global->LDS, 16B per lane; LDS dest = wave-uniform base + lane*16
__device__ __forceinline__ void gload_lds16(const ushort* g, ushort* l) {
    __builtin_amdgcn_global_load_lds(
        (const __attribute__((address_space(1))) unsigned int*)g,
        (__attribute__((address_space(3))) unsigned int*)l, 16, 0, 0);
}

// ---------------- top-7 per row of coeff (rows 0..255), emit COO for cols<256 -----
__global__ __launch_bounds__(256)
void topk_kernel(const float* __restrict__ coeff,
                 int* __restrict__ coo_cnt, int* __restrict__ coo_m,
                 int* __restrict__ coo_p, float* __restrict__ coo_v)
{
    int row = blockIdx.x;            // = m index, 0..255
    int tid = threadIdx.x;
    const float* crow = coeff + (long)row * 2048;
    float av[8];
#pragma unroll
    for (int i = 0; i < 8; ++i) av[i] = fabsf(crow[tid + 256 * i]);
    __shared__ unsigned long long red[256];
    for (int t = 0; t < 7; ++t) {
        float mx = -1.f; int mi = 0;
#pragma unroll
        for (int i = 0; i < 8; ++i) if (av[i] > mx) { mx = av[i]; mi = i; }
        unsigned col = (unsigned)(tid + 256 * mi);
        unsigned long long pk = ((unsigned long long)__float_as_uint(mx) << 32)
                              | (unsigned long long)(2048u - col); // tie -> smaller col
        red[tid] = pk; __syncthreads();
        for (int s = 128; s > 0; s >>= 1) {
            if (tid < s) { if (red[tid + s] > red[tid]) red[tid] = red[tid + s]; }
            __syncthreads();
        }
        unsigned long long w = red[0];
        __syncthreads();
        unsigned wcol = 2048u - (unsigned)(w & 0xffffffffu);
        if ((wcol & 255u) == (unsigned)tid) av[wcol >> 8] = -1.f; // consume
        if (tid == 0 && wcol < 256u) {
            int pos = atomicAdd(coo_cnt, 1);
            coo_m[pos] = row; coo_p[pos] = (int)wcol; coo_v[pos] = crow[wcol];
        }
    }
}

// ---------------- COO -> CSC (single block) ----------------
__global__ __launch_bounds__(256)
void csc_kernel(const int* __restrict__ coo_cnt, const int* __restrict__ coo_m,
                const int* __restrict__ coo_p, const float* __restrict__ coo_v,
                int* __restrict__ csc_ptr, int* __restrict__ csc_m, float* __restrict__ csc_v)
{
    __shared__ int cnt[256];
    __shared__ int off[257];
    __shared__ int cur[256];
    int tid = threadIdx.x;
    cnt[tid] = 0;
    __syncthreads();
    int n = *coo_cnt; if (n > MAXNNZ) n = MAXNNZ;
    for (int e = tid; e < n; e += 256) atomicAdd(&cnt[coo_p[e]], 1);
    __syncthreads();
    if (tid == 0) {
        int s = 0;
        for (int p = 0; p < 256; ++p) { off[p] = s; s += cnt[p]; }
        off[256] = s;
    }
    __syncthreads();
    csc_ptr[tid] = off[tid];
    if (tid == 0) csc_ptr[256] = off[256];
    cur[tid] = off[tid];
    __syncthreads();
    for (int e = tid; e < n; e += 256) {
        int p = coo_p[e];
        int pos = atomicAdd(&cur[p], 1);
        csc_m[pos] = coo_m[e];
        csc_v[pos] = coo_v[e];
    }
}

// ---------------- fp32 -> bf16 convert, 4 tensors in one launch ----------------
__global__ void cvt4_kernel(const float* a0, ushort* d0, int n0,
                            const float* a1, ushort* d1, int n1,
                            const float* a2, ushort* d2, int n2,
                            const float* a3, ushort* d3, int n3)
{
    const float* s; ushort* d; int n;
    switch (blockIdx.y) {
        case 0: s = a0; d = d0; n = n0; break;
        case 1: s = a1; d = d1; n = n1; break;
        case 2: s = a2; d = d2; n = n2; break;
        default: s = a3; d = d3; n = n3; break;
    }
    int nv = n >> 2;
    for (int i = blockIdx.x * blockDim.x + threadIdx.x; i < nv; i += gridDim.x * blockDim.x) {
        fx4 v = ((const fx4*)s)[i];
        ushort4v o;
        o[0] = f2bf(v[0]); o[1] = f2bf(v[1]); o[2] = f2bf(v[2]); o[3] = f2bf(v[3]);
        ((ushort4v*)d)[i] = o;
    }
}

// ---------------- transpose f32 [z][R][C] -> bf16 [z][C][R] ----------------
__global__ __launch_bounds__(256)
void transpose_f32_bf16(const float* __restrict__ in, ushort* __restrict__ out, int R, int C)
{
    int z = blockIdx.z;
    const float* ib = in + (long)z * R * C;
    ushort* ob = out + (long)z * R * C;
    __shared__ ushort tile[64][72];
    int r0 = blockIdx.x * 64, c0 = blockIdx.y * 64;
    int tid = threadIdx.x;
    int rl = tid >> 2, sg = tid & 3;
#pragma unroll
    for (int h = 0; h < 4; ++h) {
        fx4 v = *(const fx4*)(ib + (long)(r0 + rl) * C + c0 + h * 16 + sg * 4);
#pragma unroll
        for (int i = 0; i < 4; ++i) tile[h * 16 + sg * 4 + i][rl] = f2bf(v[i]);
    }
    __syncthreads();
    int cl = rl;
#pragma unroll
    for (int h = 0; h < 2; ++h) {
        ushort8 vv = *(const ushort8*)(&tile[cl][h * 32 + sg * 8]);
        *(ushort8*)(ob + (long)(c0 + cl) * R + r0 + h * 32 + sg * 8) = vv;
    }
}

// ---------------- K-combine: ktc[z][p][d] = sum_e csc_v[e] * kbT[z][m_e][d] --------
__global__ __launch_bounds__(256)
void kcomb_kernel(const ushort* __restrict__ kbT, ushort* __restrict__ ktc,
                  const int* __restrict__ csc_ptr, const int* __restrict__ csc_m,
                  const float* __restrict__ csc_v)
{
    int z = blockIdx.y;
    int tid = threadIdx.x;
    int p = blockIdx.x * 64 + (tid >> 2);
    int d0 = (tid & 3) * 64;
    const ushort* src = kbT + (long)z * 65536;
    float acc[64];
#pragma unroll
    for (int i = 0; i < 64; ++i) acc[i] = 0.f;
    int e0 = csc_ptr[p], e1 = csc_ptr[p + 1];
    for (int e = e0; e < e1; ++e) {
        const ushort* row = src + csc_m[e] * 256 + d0;
        float c = csc_v[e];
#pragma unroll
        for (int u = 0; u < 8; ++u) {
            ushort8 v = *(const ushort8*)(row + u * 8);
#pragma unroll
            for (int t = 0; t < 8; ++t) acc[u * 8 + t] += bf2f(v[t]) * c;
        }
    }
    ushort* dst = ktc + (long)z * 65536 + (long)p * 256 + d0;
#pragma unroll
    for (int u = 0; u < 8; ++u) {
        ushort8 o;
#pragma unroll
        for (int t = 0; t < 8; ++t) o[t] = f2bf(acc[u * 8 + t]);
        *(ushort8*)(dst + u * 8) = o;
    }
}

// ---------------- fused attention v3: T=QK~^T/s, softmax, O = P V^T ----------------
// Block = (z, n-half): 512 blocks x 256 threads (4 waves), LDS ~70KB -> 2 blocks/CU.
// Q staged once into LDS (PQ, reused as P then O-retile). K and V fragments loaded
// DIRECTLY global->VGPR (L2/L3-resident; common-mistake #7: don't stage cache-fit
// data). Only 6 block-wide __syncthreads; waves run free between them.
__global__ __launch_bounds__(256, 2)
void attn_kernel(const ushort* __restrict__ Q, const ushort* __restrict__ Kt,
                 const ushort* __restrict__ V, ushort* __restrict__ O,
                 const float* __restrict__ scale_src)
{
    __shared__ __align__(16) ushort PQ[32768];      // 64 KB: Q-half -> P -> O retile
    __shared__ float rmax[4][128];
    __shared__ float rsum[4][128];

    int bid = blockIdx.x;
    int hf = bid >> 8, z = bid & 255;               // (z,0),(z,1) same XCD (z%8)
    int b = z >> 3, h = z & 7;
    const ushort* Qz = Q + (long)z * 65536 + (long)hf * 32768;   // [128 n][256 d]
    const ushort* Kz = Kt + (long)z * 65536;                     // [256 p][256 d]
    const ushort* Vz = V + (long)b * 524288 + (long)h * 65536;   // [256 d][256 p]
    ushort* Ob = O + (long)b * 524288 + (long)h * 256 + (long)hf * 128 * 2048;

    int tid = threadIdx.x;
    int wave = tid >> 6, lane = tid & 63;           // wave = p/d quarter (0..3)
    int l16 = lane & 15, quad = lane >> 4;
    int key = l16 & 7;

    // ---- stage Q half [128][256] into PQ, swizzled via pre-swizzled source ----
    // chunk c = g*256+tid: row = c>>5 = g*8 + (tid>>5), phys chunk = tid&31,
    // logical = (tid&31)^(row&7); row&7 = rb&7 since g*8 ≡ 0 (mod 8)
    {
        int rb = wave * 2 + (lane >> 5);            // row base (g adds multiples of 8)
        const ushort* qsrc = Qz + (long)rb * 256 + (((lane & 31) ^ (rb & 7)) * 8);
        ushort* qdst = PQ + wave * 512;
#pragma unroll
        for (int g = 0; g < 16; ++g)
            gload_lds16(qsrc + g * 2048, qdst + g * 2048);
    }

    // K fragment base: frag j rows p = wave*64 + j*16 + l16, k-chunk d = kd*32+quad*8
    const ushort* kfp = Kz + (long)(wave * 64 + l16) * 256 + quad * 8;
    const ushort* vfp = Vz + (long)(wave * 64 + l16) * 256 + quad * 8;

    fx4 acc[8][4];
#pragma unroll
    for (int i = 0; i < 8; ++i)
#pragma unroll
        for (int j = 0; j < 4; ++j) acc[i][j] = (fx4){0.f, 0.f, 0.f, 0.f};

    // pre-issue K frags for kd=0 (global->VGPR, no LDS dependence)
    short8 bfn[4];
#pragma unroll
    for (int j = 0; j < 4; ++j) bfn[j] = *(const short8*)(kfp + j * 4096);

    __syncthreads();                                 // Q staged (+ bf0 ready)

    float sc = 1.0f / scale_src[0];

    // ---- phase 1: S[128 n][64 p(wave)] = Q K~^T, k = d (8 steps of 32) ----
#pragma unroll
    for (int kd = 0; kd < 8; ++kd) {
        short8 bf[4];
#pragma unroll
        for (int j = 0; j < 4; ++j) bf[j] = bfn[j];
        if (kd < 7) {
#pragma unroll
            for (int j = 0; j < 4; ++j)
                bfn[j] = *(const short8*)(kfp + j * 4096 + (kd + 1) * 32);
        }
        short8 af[8];
#pragma unroll
        for (int i = 0; i < 8; ++i)
            af[i] = *(const short8*)(PQ + (i * 16 + l16) * 256 + (((kd * 4 + quad) ^ key) * 8));
        __builtin_amdgcn_s_setprio(1);
#pragma unroll
        for (int i = 0; i < 8; ++i)
#pragma unroll
            for (int j = 0; j < 4; ++j)
                acc[i][j] = __builtin_amdgcn_mfma_f32_16x16x32_bf16(af[i], bf[j], acc[i][j], 0, 0, 0);
        __builtin_amdgcn_s_setprio(0);
    }

    // ---- softmax over p (rows n) ----
#pragma unroll
    for (int i = 0; i < 8; ++i)
#pragma unroll
        for (int j = 0; j < 4; ++j)
#pragma unroll
            for (int r = 0; r < 4; ++r) acc[i][j][r] *= sc;

    float lm[8][4];
#pragma unroll
    for (int i = 0; i < 8; ++i)
#pragma unroll
        for (int r = 0; r < 4; ++r) {
            float m = -1e30f;
#pragma unroll
            for (int j = 0; j < 4; ++j) m = fmaxf(m, acc[i][j][r]);
            lm[i][r] = m;
        }
#pragma unroll
    for (int d = 1; d < 16; d <<= 1)
#pragma unroll
        for (int i = 0; i < 8; ++i)
#pragma unroll
            for (int r = 0; r < 4; ++r) lm[i][r] = fmaxf(lm[i][r], __shfl_xor(lm[i][r], d, 16));
    if (l16 == 0) {
#pragma unroll
        for (int i = 0; i < 8; ++i)
#pragma unroll
            for (int r = 0; r < 4; ++r)
                rmax[wave][i * 16 + quad * 4 + r] = lm[i][r];
    }
    __syncthreads();

    float ls[8][4];
#pragma unroll
    for (int i = 0; i < 8; ++i)
#pragma unroll
        for (int r = 0; r < 4; ++r) {
            int row = i * 16 + quad * 4 + r;
            float M = fmaxf(fmaxf(rmax[0][row], rmax[1][row]),
                            fmaxf(rmax[2][row], rmax[3][row]));
            float s = 0.f;
#pragma unroll
            for (int j = 0; j < 4; ++j) {
                float e = __expf(acc[i][j][r] - M);
                acc[i][j][r] = e;
                s += e;
            }
            ls[i][r] = s;
        }
#pragma unroll
    for (int d = 1; d < 16; d <<= 1)
#pragma unroll
        for (int i = 0; i < 8; ++i)
#pragma unroll
            for (int r = 0; r < 4; ++r) ls[i][r] += __shfl_xor(ls[i][r], d, 16);
    if (l16 == 0) {
#pragma unroll
        for (int i = 0; i < 8; ++i)
#pragma unroll
            for (int r = 0; r < 4; ++r)
                rsum[wave][i * 16 + quad * 4 + r] = ls[i][r];
    }
    __syncthreads();

    // pre-issue V frags kp=0 (independent of P) so PV starts hot
    short8 vfn[4];
#pragma unroll
    for (int j = 0; j < 4; ++j) vfn[j] = *(const short8*)(vfp + j * 4096);

    // normalize + write P into PQ (Q dead), swizzled chunk ^= row&7
#pragma unroll
    for (int i = 0; i < 8; ++i)
#pragma unroll
        for (int r = 0; r < 4; ++r) {
            int row = i * 16 + quad * 4 + r;
            float inv = 1.0f / (rsum[0][row] + rsum[1][row] + rsum[2][row] + rsum[3][row]);
            int k2 = row & 7;
#pragma unroll
            for (int j = 0; j < 4; ++j) {
                int p = wave * 64 + j * 16 + l16;
                PQ[row * 256 + ((((p >> 3) ^ k2) << 3) | (p & 7))] = f2bf(acc[i][j][r] * inv);
            }
        }
    __syncthreads();

    // ---- phase 2: O[128 n][64 d(wave)] = P V^T, k = p (8 steps of 32) ----
    fx4 acc2[8][4];
#pragma unroll
    for (int i = 0; i < 8; ++i)
#pragma unroll
        for (int j = 0; j < 4; ++j) acc2[i][j] = (fx4){0.f, 0.f, 0.f, 0.f};

#pragma unroll
    for (int kp = 0; kp < 8; ++kp) {
        short8 vf[4];
#pragma unroll
        for (int j = 0; j < 4; ++j) vf[j] = vfn[j];
        if (kp < 7) {
#pragma unroll
            for (int j = 0; j < 4; ++j)
                vfn[j] = *(const short8*)(vfp + j * 4096 + (kp + 1) * 32);
        }
        short8 pa[8];
#pragma unroll
        for (int i = 0; i < 8; ++i)
            pa[i] = *(const short8*)(PQ + (i * 16 + l16) * 256 + (((kp * 4 + quad) ^ key) * 8));
        __builtin_amdgcn_s_setprio(1);
#pragma unroll
        for (int i = 0; i < 8; ++i)
#pragma unroll
            for (int j = 0; j < 4; ++j)
                acc2[i][j] = __builtin_amdgcn_mfma_f32_16x16x32_bf16(pa[i], vf[j], acc2[i][j], 0, 0, 0);
        __builtin_amdgcn_s_setprio(0);
    }

    // ---- epilogue: retile O through PQ (dead), coalesced 512B-row stores ----
    __syncthreads();                                // all waves done reading P
#pragma unroll
    for (int i = 0; i < 8; ++i)
#pragma unroll
        for (int j = 0; j < 4; ++j) {
            int rowb = i * 16 + quad * 4;
            int col = wave * 64 + j * 16 + l16;
#pragma unroll
            for (int rr = 0; rr < 4; ++rr) {
                int row = rowb + rr;
                PQ[row * 256 + ((((col >> 3) ^ (row & 7)) << 3) | (col & 7))]
                    = f2bf(acc2[i][j][rr]);
            }
        }
    __syncthreads();
#pragma unroll
    for (int pass = 0; pass < 16; ++pass) {
        int row = pass * 8 + (tid >> 5), ch = tid & 31;
        ushort8 vv = *(const ushort8*)(PQ + row * 256 + ((ch ^ (row & 7)) << 3));
        *(ushort8*)(Ob + (long)row * 2048 + ch * 8) = vv;
    }
}

// ---------------- 256x256-tile NT GEMM, 8 waves, fine-phase pipelined --------------
// 4-deep LDS ring (BK=32), 2 phases per K-tile; counted vmcnt; swizzled LDS.
// MODE 4: merged QKV, A=[6144][512] wqkv, B=[8192][512] xT; sec = m0>>11 uniform.
// MODE 5: final: A=[2048][2048] wob, B=[8192][2048] obT; f32 out + bias (direct).
template<int MODE>
__global__ __launch_bounds__(512, 2)
void gemm256(const ushort* __restrict__ A, const ushort* __restrict__ B,
             void* __restrict__ C,
             const float* __restrict__ bias0, const float* __restrict__ bias1,
             const float* __restrict__ bias2,
             int MT, int K)
{
    __shared__ __align__(16) ushort lds[4][2][8192];   // 128 KiB ring: 4 x (A,B) x 256x32

    int nwg = gridDim.x;
    int bid = blockIdx.x;
    int cpx = nwg >> 3;                        // nwg % 8 == 0 guaranteed by launch
    int swz = (bid & 7) * cpx + (bid >> 3);    // XCD-aware swizzle (bijective)
    int mt = swz % MT, nt = swz / MT;
    int m0 = mt << 8, n0 = nt << 8;

    int tid = threadIdx.x;
    int wave = tid >> 6, lane = tid & 63;
    int wr = wave >> 2, wc = wave & 3;         // 2x4 wave grid; per-wave C = 128x64
    int l16 = lane & 15, quad = lane >> 4;

    int lc = (((lane & 3) ^ ((lane >> 3) & 3))) * 8;
    const ushort* gA0 = A + (long long)(m0 + wave * 16 + (lane >> 2)) * K + lc;
    const ushort* gA1 = gA0 + (long long)128 * K;
    const ushort* gB0 = B + (long long)(n0 + wave * 16 + (lane >> 2)) * K + lc;
    const ushort* gB1 = gB0 + (long long)128 * K;
    int ldso = wave * 512;                     // wave's 1KB stripe (ushorts)

    int rsw = ((l16 >> 1) & 3) * 8;
    int aoff = (wr * 128 + l16) * 32 + ((quad * 8) ^ rsw);
    int boff = (wc * 64 + l16) * 32 + ((quad * 8) ^ rsw);

    fx4 acc[8][4];
#pragma unroll
    for (int i = 0; i < 8; ++i)
#pragma unroll
        for (int j = 0; j < 4; ++j) acc[i][j] = (fx4){0.f, 0.f, 0.f, 0.f};

    auto stageA = [&](int b, int kc) {
        gload_lds16(gA0 + kc, &lds[b][0][ldso]);
        gload_lds16(gA1 + kc, &lds[b][0][4096 + ldso]);
    };
    auto stageB = [&](int b, int kc) {
        gload_lds16(gB0 + kc, &lds[b][1][ldso]);
        gload_lds16(gB1 + kc, &lds[b][1][4096 + ldso]);
    };

    short8 af[4], bf[4];
    auto readA = [&](int b, int half) {
        const ushort* p = &lds[b][0][aoff + half * 2048];
#pragma unroll
        for (int i = 0; i < 4; ++i) af[i] = *(const short8*)(p + i * 512);
    };
    auto readB = [&](int b) {
        const ushort* p = &lds[b][1][boff];
#pragma unroll
        for (int j = 0; j < 4; ++j) bf[j] = *(const short8*)(p + j * 512);
    };
    auto mma = [&](int half) {
        __builtin_amdgcn_s_setprio(1);
#pragma unroll
        for (int i = 0; i < 4; ++i)
#pragma unroll
            for (int j = 0; j < 4; ++j)
                acc[half * 4 + i][j] =
                    __builtin_amdgcn_mfma_f32_16x16x32_bf16(af[i], bf[j], acc[half * 4 + i][j], 0, 0, 0);
        __builtin_amdgcn_s_setprio(0);
    };

    int NT = K >> 5;
    stageA(0, 0);  stageB(0, 0);
    stageA(1, 32); stageB(1, 32);
    stageA(2, 64); stageB(2, 64);
    asm volatile("s_waitcnt vmcnt(8)" ::: "memory");
    __builtin_amdgcn_s_barrier();

    for (int t = 0; t < NT; ++t) {
        int b = t & 3;
        readA(b, 0); readB(b);
        if (t + 3 < NT) stageA((t + 3) & 3, (t + 3) << 5);
        __builtin_amdgcn_s_barrier();
        asm volatile("s_waitcnt lgkmcnt(0)" ::: "memory");
        __builtin_amdgcn_sched_barrier(0);
        mma(0);
        __builtin_amdgcn_s_barrier();
        readA(b, 1);
        if (t + 3 < NT) {
            stageB((t + 3) & 3, (t + 3) << 5);
            asm volatile("s_waitcnt vmcnt(8)" ::: "memory");
        } else if (t + 2 < NT) {
            asm volatile("s_waitcnt vmcnt(4)" ::: "memory");
        } else if (t + 1 < NT) {
            asm volatile("s_waitcnt vmcnt(0)" ::: "memory");
        }
        __builtin_amdgcn_s_barrier();
        asm volatile("s_waitcnt lgkmcnt(0)" ::: "memory");
        __builtin_amdgcn_sched_barrier(0);
        mma(1);
        __builtin_amdgcn_s_barrier();
    }

    if (MODE == 5) {
        float* Cf = (float*)C + (long long)nt * 524288;
#pragma unroll
        for (int i = 0; i < 8; ++i) {
            int m = m0 + wr * 128 + i * 16 + quad * 4;
#pragma unroll
            for (int j = 0; j < 4; ++j) {
                int n = wc * 64 + j * 16 + l16;
                float* dst = Cf + (long long)m * 256 + n;
#pragma unroll
                for (int r = 0; r < 4; ++r)
                    dst[(long)r * 256] = acc[i][j][r] + bias0[m + r];
            }
        }
        return;
    }

    if (MODE == 4) {
        int sec = m0 >> 11;
        int ms0 = m0 & 2047;
        ushort* ct = &lds[0][0][0];            // re-tile buffer: 128 x 264 ushorts
        if (sec < 2) {
            const float* bs = (sec == 0) ? bias0 : bias1;
            ushort* base = (ushort*)C + (long long)sec * 16777216
                         + (long long)nt * 524288 + (long long)(ms0 >> 8) * 65536;
#pragma unroll
            for (int hh = 0; hh < 2; ++hh) {
                if ((wc >> 1) == hh) {
#pragma unroll
                    for (int i = 0; i < 8; ++i)
#pragma unroll
                        for (int j = 0; j < 4; ++j) {
                            int nl = (wc & 1) * 64 + j * 16 + l16;
                            int ml = wr * 128 + i * 16 + quad * 4;
                            ushort4v pk;
#pragma unroll
                            for (int r = 0; r < 4; ++r)
                                pk[r] = f2bf(acc[i][j][r] + bs[ms0 + ml + r]);
                            *(ushort4v*)(ct + nl * 264 + ml) = pk;
                        }
                }
                __syncthreads();
                int row = tid & 127, c0 = (tid >> 7) * 64;
                ushort* dst = base + (long long)(hh * 128 + row) * 256 + c0;
                const ushort* src = ct + row * 264 + c0;
#pragma unroll
                for (int u = 0; u < 8; ++u)
                    *(ushort8*)(dst + u * 8) = *(const ushort8*)(src + u * 8);
                __syncthreads();
            }
        } else {
            ushort* base = (ushort*)C + 33554432LL + (long long)nt * 524288
                         + (long long)ms0 * 256;
#pragma unroll
            for (int hh = 0; hh < 2; ++hh) {
                if (wr == hh) {
#pragma unroll
                    for (int i = 0; i < 8; ++i)
#pragma unroll
                        for (int j = 0; j < 4; ++j) {
                            int nl = wc * 64 + j * 16 + l16;
                            int ml = i * 16 + quad * 4;
#pragma unroll
                            for (int r = 0; r < 4; ++r)
                                ct[(ml + r) * 264 + nl] =
                                    f2bf(acc[i][j][r] + bias2[ms0 + hh * 128 + ml + r]);
                        }
                }
                __syncthreads();
                int row = tid & 127, c0 = (tid >> 7) * 64;
                ushort* dst = base + (long long)(hh * 128 + row) * 256 + c0;
                const ushort* src = ct + row * 264 + c0;
#pragma unroll
                for (int u = 0; u < 8; ++u)
                    *(ushort8*)(dst + u * 8) = *(const ushort8*)(src + u * 8);
                __syncthreads();
            }
        }
        return;
    }
}

extern "C" void kernel_launch(void* const* d_in, const int* in_sizes, int n_in,
                              void* d_out, int out_size, void* d_ws, size_t ws_size,
                              hipStream_t stream)
{
    const float* x     = (const float*)d_in[0];
    const float* Wq    = (const float*)d_in[1];
    const float* bq    = (const float*)d_in[2];
    const float* Wk    = (const float*)d_in[3];
    const float* bk    = (const float*)d_in[4];
    const float* Wv    = (const float*)d_in[5];
    const float* bv    = (const float*)d_in[6];
    const float* Wo    = (const float*)d_in[7];
    const float* bo    = (const float*)d_in[8];
    const float* coeff = (const float*)d_in[9];
    const float* scale = (const float*)d_in[10];
    float* out = (float*)d_out;

    size_t o = 0;
    char* w = (char*)d_ws;
    auto take = [&](size_t bytes) -> void* {
        void* p = w + o; o += (bytes + 255) & ~(size_t)255; return p;
    };
    int*    coo_cnt = (int*)take(4);
    int*    coo_m   = (int*)take(MAXNNZ * 4);
    int*    coo_p   = (int*)take(MAXNNZ * 4);
    float*  coo_v   = (float*)take(MAXNNZ * 4);
    int*    csc_ptr = (int*)take(257 * 4);
    int*    csc_m   = (int*)take(MAXNNZ * 4);
    float*  csc_v   = (float*)take(MAXNNZ * 4);
    ushort* wqkv = (ushort*)take(6144L * 512 * 2);       // [wq;wk;wv] stacked
    ushort* wob  = (ushort*)take(2048L * 2048 * 2);
    ushort* xT   = (ushort*)take(32L * 256 * 512 * 2);   // [b][n][cin] == [8192][512]
    ushort* qkv  = (ushort*)take(3 * 16777216L * 2);     // qbT | kbT | vb contiguous
    ushort* qbT = qkv;                                   // [b][h][n][d]
    ushort* kbT = qkv + 16777216L;                       // [b][h][m][d]
    ushort* vb  = qkv + 33554432L;                       // [b][2048][256]
    ushort* ktc = (ushort*)take(16777216L * 2);          // [z][p][d]
    // alias: kbT dead after kcomb -> obT lives there (disjoint from qbT/vb/ktc reads)
    ushort* obT  = kbT;                                  // [8192][2048]
    (void)in_sizes; (void)n_in; (void)out_size; (void)ws_size;

    // 1) sparsity structure
    hipMemsetAsync(coo_cnt, 0, 4, stream);
    topk_kernel<<<256, 256, 0, stream>>>(coeff, coo_cnt, coo_m, coo_p, coo_v);
    csc_kernel<<<1, 256, 0, stream>>>(coo_cnt, coo_m, coo_p, coo_v, csc_ptr, csc_m, csc_v);

    // 2) weight converts + x transpose
    cvt4_kernel<<<dim3(1024, 4, 1), 256, 0, stream>>>(
        Wq, wqkv, 2048 * 512, Wk, wqkv + 2048L * 512, 2048 * 512,
        Wv, wqkv + 4096L * 512, 2048 * 512, Wo, wob, 2048 * 2048);
    transpose_f32_bf16<<<dim3(8, 4, 32), 256, 0, stream>>>(x, xT, 512, 256);

    // 3) merged QKV projection: [6144,512] x [8192,512]^T, 256^2 pipelined tiles
    gemm256<4><<<dim3(768, 1, 1), dim3(512, 1, 1), 0, stream>>>(
        wqkv, xT, qkv, bq, bk, bv, 24, 512);

    // 4) K-combine with sparse coeff: ktc[z][p][d]
    kcomb_kernel<<<dim3(4, 256), 256, 0, stream>>>(kbT, ktc, csc_ptr, csc_m, csc_v);

    // 5+6) fused attention v3: softmax(Q^T K~ / s) V -> obT [8192][2048]
    attn_kernel<<<512, 256, 0, stream>>>(qbT, ktc, vb, obT, scale);

    // 7) merged final projection: [2048,2048] x [8192,2048]^T -> out f32 [b][2048][256]
    gemm256<5><<<dim3(256, 1, 1), dim3(512, 1, 1), 0, stream>>>(
        wob, obT, out, bo, nullptr, nullptr, 8, 2048);
}

// Round 7
// 364.227 us; speedup vs baseline: 1.1545x; 1.0462x over previous
//
#include <hip/hip_runtime.h>

typedef unsigned short ushort;
typedef __attribute__((ext_vector_type(8))) short short8;
typedef __attribute__((ext_vector_type(8))) unsigned short ushort8;
typedef __attribute__((ext_vector_type(4))) unsigned short ushort4v;
typedef __attribute__((ext_vector_type(4))) float fx4;

#define MAXNNZ (256*7)

__device__ __forceinline__ ushort f2bf(float f) {
    union { float f; unsigned u; } v; v.f = f;
    unsigned r = v.u + 0x7fffu + ((v.u >> 16) & 1u);
    return (ushort)(r >> 16);
}

__device__ __forceinline__ float bf2f(ushort b) {
    union { unsigned u; float f; } v; v.u = ((unsigned)b) << 16;
    return v.f;
}

// async global->LDS, 16B per lane; LDS dest = wave-uniform base + lane*16
__device__ __forceinline__ void gload_lds16(const ushort* g, ushort* l) {
    __builtin_amdgcn_global_load_lds(
        (const __attribute__((address_space(1))) unsigned int*)g,
        (__attribute__((address_space(3))) unsigned int*)l, 16, 0, 0);
}

// ---------------- top-7 per row of coeff (rows 0..255), emit COO for cols<256 -----
__global__ __launch_bounds__(256)
void topk_kernel(const float* __restrict__ coeff,
                 int* __restrict__ coo_cnt, int* __restrict__ coo_m,
                 int* __restrict__ coo_p, float* __restrict__ coo_v)
{
    int row = blockIdx.x;            // = m index, 0..255
    int tid = threadIdx.x;
    const float* crow = coeff + (long)row * 2048;
    float av[8];
#pragma unroll
    for (int i = 0; i < 8; ++i) av[i] = fabsf(crow[tid + 256 * i]);
    __shared__ unsigned long long red[256];
    for (int t = 0; t < 7; ++t) {
        float mx = -1.f; int mi = 0;
#pragma unroll
        for (int i = 0; i < 8; ++i) if (av[i] > mx) { mx = av[i]; mi = i; }
        unsigned col = (unsigned)(tid + 256 * mi);
        unsigned long long pk = ((unsigned long long)__float_as_uint(mx) << 32)
                              | (unsigned long long)(2048u - col); // tie -> smaller col
        red[tid] = pk; __syncthreads();
        for (int s = 128; s > 0; s >>= 1) {
            if (tid < s) { if (red[tid + s] > red[tid]) red[tid] = red[tid + s]; }
            __syncthreads();
        }
        unsigned long long w = red[0];
        __syncthreads();
        unsigned wcol = 2048u - (unsigned)(w & 0xffffffffu);
        if ((wcol & 255u) == (unsigned)tid) av[wcol >> 8] = -1.f; // consume
        if (tid == 0 && wcol < 256u) {
            int pos = atomicAdd(coo_cnt, 1);
            coo_m[pos] = row; coo_p[pos] = (int)wcol; coo_v[pos] = crow[wcol];
        }
    }
}

// ---------------- COO -> CSC (single block) + per-column value sums ----------------
__global__ __launch_bounds__(256)
void csc_kernel(const int* __restrict__ coo_cnt, const int* __restrict__ coo_m,
                const int* __restrict__ coo_p, const float* __restrict__ coo_v,
                int* __restrict__ csc_ptr, int* __restrict__ csc_m,
                float* __restrict__ csc_v, float* __restrict__ csum)
{
    __shared__ int cnt[256];
    __shared__ int off[257];
    __shared__ int cur[256];
    int tid = threadIdx.x;
    cnt[tid] = 0;
    __syncthreads();
    int n = *coo_cnt; if (n > MAXNNZ) n = MAXNNZ;
    for (int e = tid; e < n; e += 256) atomicAdd(&cnt[coo_p[e]], 1);
    __syncthreads();
    if (tid == 0) {
        int s = 0;
        for (int p = 0; p < 256; ++p) { off[p] = s; s += cnt[p]; }
        off[256] = s;
    }
    __syncthreads();
    csc_ptr[tid] = off[tid];
    if (tid == 0) csc_ptr[256] = off[256];
    cur[tid] = off[tid];
    __syncthreads();
    for (int e = tid; e < n; e += 256) {
        int p = coo_p[e];
        int pos = atomicAdd(&cur[p], 1);
        csc_m[pos] = coo_m[e];
        csc_v[pos] = coo_v[e];
    }
    __syncthreads();
    {   // column value-sum (for bias scaling of combined-K path)
        float s = 0.f;
        int e0 = off[tid], e1 = off[tid] + cnt[tid];
        for (int e = e0; e < e1; ++e) s += csc_v[e];
        csum[tid] = s;
    }
}

// ---------------- fp32 -> bf16 convert, 4 tensors in one launch ----------------
__global__ void cvt4_kernel(const float* a0, ushort* d0, int n0,
                            const float* a1, ushort* d1, int n1,
                            const float* a2, ushort* d2, int n2,
                            const float* a3, ushort* d3, int n3)
{
    const float* s; ushort* d; int n;
    switch (blockIdx.y) {
        case 0: s = a0; d = d0; n = n0; break;
        case 1: s = a1; d = d1; n = n1; break;
        case 2: s = a2; d = d2; n = n2; break;
        default: s = a3; d = d3; n = n3; break;
    }
    int nv = n >> 2;
    for (int i = blockIdx.x * blockDim.x + threadIdx.x; i < nv; i += gridDim.x * blockDim.x) {
        fx4 v = ((const fx4*)s)[i];
        ushort4v o;
        o[0] = f2bf(v[0]); o[1] = f2bf(v[1]); o[2] = f2bf(v[2]); o[3] = f2bf(v[3]);
        ((ushort4v*)d)[i] = o;
    }
}

// ---------------- transpose f32 [z][R][C] -> bf16 [z][C][R] ----------------
__global__ __launch_bounds__(256)
void transpose_f32_bf16(const float* __restrict__ in, ushort* __restrict__ out, int R, int C)
{
    int z = blockIdx.z;
    const float* ib = in + (long)z * R * C;
    ushort* ob = out + (long)z * R * C;
    __shared__ ushort tile[64][72];
    int r0 = blockIdx.x * 64, c0 = blockIdx.y * 64;
    int tid = threadIdx.x;
    int rl = tid >> 2, sg = tid & 3;
#pragma unroll
    for (int h = 0; h < 4; ++h) {
        fx4 v = *(const fx4*)(ib + (long)(r0 + rl) * C + c0 + h * 16 + sg * 4);
#pragma unroll
        for (int i = 0; i < 4; ++i) tile[h * 16 + sg * 4 + i][rl] = f2bf(v[i]);
    }
    __syncthreads();
    int cl = rl;
#pragma unroll
    for (int h = 0; h < 2; ++h) {
        ushort8 vv = *(const ushort8*)(&tile[cl][h * 32 + sg * 8]);
        *(ushort8*)(ob + (long)(c0 + cl) * R + r0 + h * 32 + sg * 8) = vv;
    }
}

// ---------------- x-combine: xc[b][p][c] = sum_e csc_v[e] * xT[b][m_e][c] ----------
// (sparse combine commuted before the K-projection: K~ = (C^T X) Wk^T)
__global__ __launch_bounds__(256)
void xcomb_kernel(const ushort* __restrict__ xT, ushort* __restrict__ xc,
                  const int* __restrict__ csc_ptr, const int* __restrict__ csc_m,
                  const float* __restrict__ csc_v)
{
    int b = blockIdx.y;
    int tid = threadIdx.x;
    int p = blockIdx.x * 32 + (tid >> 3);
    int c0 = (tid & 7) * 64;
    const ushort* src = xT + (long)b * 131072;      // 256 x 512
    float acc[64];
#pragma unroll
    for (int i = 0; i < 64; ++i) acc[i] = 0.f;
    int e0 = csc_ptr[p], e1 = csc_ptr[p + 1];
    for (int e = e0; e < e1; ++e) {
        const ushort* row = src + csc_m[e] * 512 + c0;
        float c = csc_v[e];
#pragma unroll
        for (int u = 0; u < 8; ++u) {
            ushort8 v = *(const ushort8*)(row + u * 8);
#pragma unroll
            for (int t = 0; t < 8; ++t) acc[u * 8 + t] += bf2f(v[t]) * c;
        }
    }
    ushort* dst = xc + (long)b * 131072 + (long)p * 512 + c0;
#pragma unroll
    for (int u = 0; u < 8; ++u) {
        ushort8 o;
#pragma unroll
        for (int t = 0; t < 8; ++t) o[t] = f2bf(acc[u * 8 + t]);
        *(ushort8*)(dst + u * 8) = o;
    }
}

// ---------------- fused attention v3: T=QK~^T/s, softmax, O = P V^T ----------------
// Block = (z, n-half): 512 blocks x 256 threads (4 waves), LDS ~70KB -> 2 blocks/CU.
// Q staged once into LDS (PQ, reused as P then O-retile). K and V fragments loaded
// DIRECTLY global->VGPR (L2/L3-resident). Only 6 block-wide __syncthreads.
__global__ __launch_bounds__(256, 2)
void attn_kernel(const ushort* __restrict__ Q, const ushort* __restrict__ Kt,
                 const ushort* __restrict__ V, ushort* __restrict__ O,
                 const float* __restrict__ scale_src)
{
    __shared__ __align__(16) ushort PQ[32768];      // 64 KB: Q-half -> P -> O retile
    __shared__ float rmax[4][128];
    __shared__ float rsum[4][128];

    int bid = blockIdx.x;
    int hf = bid >> 8, z = bid & 255;               // (z,0),(z,1) same XCD (z%8)
    int b = z >> 3, h = z & 7;
    const ushort* Qz = Q + (long)z * 65536 + (long)hf * 32768;   // [128 n][256 d]
    const ushort* Kz = Kt + (long)z * 65536;                     // [256 p][256 d]
    const ushort* Vz = V + (long)b * 524288 + (long)h * 65536;   // [256 d][256 p]
    ushort* Ob = O + (long)b * 524288 + (long)h * 256 + (long)hf * 128 * 2048;

    int tid = threadIdx.x;
    int wave = tid >> 6, lane = tid & 63;           // wave = p/d quarter (0..3)
    int l16 = lane & 15, quad = lane >> 4;
    int key = l16 & 7;

    // ---- stage Q half [128][256] into PQ, swizzled via pre-swizzled source ----
    {
        int rb = wave * 2 + (lane >> 5);            // row base (g adds multiples of 8)
        const ushort* qsrc = Qz + (long)rb * 256 + (((lane & 31) ^ (rb & 7)) * 8);
        ushort* qdst = PQ + wave * 512;
#pragma unroll
        for (int g = 0; g < 16; ++g)
            gload_lds16(qsrc + g * 2048, qdst + g * 2048);
    }

    const ushort* kfp = Kz + (long)(wave * 64 + l16) * 256 + quad * 8;
    const ushort* vfp = Vz + (long)(wave * 64 + l16) * 256 + quad * 8;

    fx4 acc[8][4];
#pragma unroll
    for (int i = 0; i < 8; ++i)
#pragma unroll
        for (int j = 0; j < 4; ++j) acc[i][j] = (fx4){0.f, 0.f, 0.f, 0.f};

    short8 bfn[4];
#pragma unroll
    for (int j = 0; j < 4; ++j) bfn[j] = *(const short8*)(kfp + j * 4096);

    __syncthreads();                                 // Q staged (+ bf0 ready)

    float sc = 1.0f / scale_src[0];

    // ---- phase 1: S[128 n][64 p(wave)] = Q K~^T, k = d (8 steps of 32) ----
#pragma unroll
    for (int kd = 0; kd < 8; ++kd) {
        short8 bf[4];
#pragma unroll
        for (int j = 0; j < 4; ++j) bf[j] = bfn[j];
        if (kd < 7) {
#pragma unroll
            for (int j = 0; j < 4; ++j)
                bfn[j] = *(const short8*)(kfp + j * 4096 + (kd + 1) * 32);
        }
        short8 af[8];
#pragma unroll
        for (int i = 0; i < 8; ++i)
            af[i] = *(const short8*)(PQ + (i * 16 + l16) * 256 + (((kd * 4 + quad) ^ key) * 8));
        __builtin_amdgcn_s_setprio(1);
#pragma unroll
        for (int i = 0; i < 8; ++i)
#pragma unroll
            for (int j = 0; j < 4; ++j)
                acc[i][j] = __builtin_amdgcn_mfma_f32_16x16x32_bf16(af[i], bf[j], acc[i][j], 0, 0, 0);
        __builtin_amdgcn_s_setprio(0);
    }

    // ---- softmax over p (rows n) ----
#pragma unroll
    for (int i = 0; i < 8; ++i)
#pragma unroll
        for (int j = 0; j < 4; ++j)
#pragma unroll
            for (int r = 0; r < 4; ++r) acc[i][j][r] *= sc;

    float lm[8][4];
#pragma unroll
    for (int i = 0; i < 8; ++i)
#pragma unroll
        for (int r = 0; r < 4; ++r) {
            float m = -1e30f;
#pragma unroll
            for (int j = 0; j < 4; ++j) m = fmaxf(m, acc[i][j][r]);
            lm[i][r] = m;
        }
#pragma unroll
    for (int d = 1; d < 16; d <<= 1)
#pragma unroll
        for (int i = 0; i < 8; ++i)
#pragma unroll
            for (int r = 0; r < 4; ++r) lm[i][r] = fmaxf(lm[i][r], __shfl_xor(lm[i][r], d, 16));
    if (l16 == 0) {
#pragma unroll
        for (int i = 0; i < 8; ++i)
#pragma unroll
            for (int r = 0; r < 4; ++r)
                rmax[wave][i * 16 + quad * 4 + r] = lm[i][r];
    }
    __syncthreads();

    float ls[8][4];
#pragma unroll
    for (int i = 0; i < 8; ++i)
#pragma unroll
        for (int r = 0; r < 4; ++r) {
            int row = i * 16 + quad * 4 + r;
            float M = fmaxf(fmaxf(rmax[0][row], rmax[1][row]),
                            fmaxf(rmax[2][row], rmax[3][row]));
            float s = 0.f;
#pragma unroll
            for (int j = 0; j < 4; ++j) {
                float e = __expf(acc[i][j][r] - M);
                acc[i][j][r] = e;
                s += e;
            }
            ls[i][r] = s;
        }
#pragma unroll
    for (int d = 1; d < 16; d <<= 1)
#pragma unroll
        for (int i = 0; i < 8; ++i)
#pragma unroll
            for (int r = 0; r < 4; ++r) ls[i][r] += __shfl_xor(ls[i][r], d, 16);
    if (l16 == 0) {
#pragma unroll
        for (int i = 0; i < 8; ++i)
#pragma unroll
            for (int r = 0; r < 4; ++r)
                rsum[wave][i * 16 + quad * 4 + r] = ls[i][r];
    }
    __syncthreads();

    short8 vfn[4];
#pragma unroll
    for (int j = 0; j < 4; ++j) vfn[j] = *(const short8*)(vfp + j * 4096);

    // normalize + write P into PQ (Q dead), swizzled chunk ^= row&7
#pragma unroll
    for (int i = 0; i < 8; ++i)
#pragma unroll
        for (int r = 0; r < 4; ++r) {
            int row = i * 16 + quad * 4 + r;
            float inv = 1.0f / (rsum[0][row] + rsum[1][row] + rsum[2][row] + rsum[3][row]);
            int k2 = row & 7;
#pragma unroll
            for (int j = 0; j < 4; ++j) {
                int p = wave * 64 + j * 16 + l16;
                PQ[row * 256 + ((((p >> 3) ^ k2) << 3) | (p & 7))] = f2bf(acc[i][j][r] * inv);
            }
        }
    __syncthreads();

    // ---- phase 2: O[128 n][64 d(wave)] = P V^T, k = p (8 steps of 32) ----
    fx4 acc2[8][4];
#pragma unroll
    for (int i = 0; i < 8; ++i)
#pragma unroll
        for (int j = 0; j < 4; ++j) acc2[i][j] = (fx4){0.f, 0.f, 0.f, 0.f};

#pragma unroll
    for (int kp = 0; kp < 8; ++kp) {
        short8 vf[4];
#pragma unroll
        for (int j = 0; j < 4; ++j) vf[j] = vfn[j];
        if (kp < 7) {
#pragma unroll
            for (int j = 0; j < 4; ++j)
                vfn[j] = *(const short8*)(vfp + j * 4096 + (kp + 1) * 32);
        }
        short8 pa[8];
#pragma unroll
        for (int i = 0; i < 8; ++i)
            pa[i] = *(const short8*)(PQ + (i * 16 + l16) * 256 + (((kp * 4 + quad) ^ key) * 8));
        __builtin_amdgcn_s_setprio(1);
#pragma unroll
        for (int i = 0; i < 8; ++i)
#pragma unroll
            for (int j = 0; j < 4; ++j)
                acc2[i][j] = __builtin_amdgcn_mfma_f32_16x16x32_bf16(pa[i], vf[j], acc2[i][j], 0, 0, 0);
        __builtin_amdgcn_s_setprio(0);
    }

    // ---- epilogue: retile O through PQ (dead), coalesced 512B-row stores ----
    __syncthreads();                                // all waves done reading P
#pragma unroll
    for (int i = 0; i < 8; ++i)
#pragma unroll
        for (int j = 0; j < 4; ++j) {
            int rowb = i * 16 + quad * 4;
            int col = wave * 64 + j * 16 + l16;
#pragma unroll
            for (int rr = 0; rr < 4; ++rr) {
                int row = rowb + rr;
                PQ[row * 256 + ((((col >> 3) ^ (row & 7)) << 3) | (col & 7))]
                    = f2bf(acc2[i][j][rr]);
            }
        }
    __syncthreads();
#pragma unroll
    for (int pass = 0; pass < 16; ++pass) {
        int row = pass * 8 + (tid >> 5), ch = tid & 31;
        ushort8 vv = *(const ushort8*)(PQ + row * 256 + ((ch ^ (row & 7)) << 3));
        *(ushort8*)(Ob + (long)row * 2048 + ch * 8) = vv;
    }
}

// ---------------- 256x256-tile NT GEMM, 8 waves, fine-phase pipelined --------------
// 4-deep LDS ring (BK=32), 2 phases per K-tile; counted vmcnt; swizzled LDS.
// MODE 4: merged QKV, A=[6144][512] wqkv; B = xT for q/v sections, B2 = xc for the
//         k section (combined-x path -> writes ktc directly, bias bk[d]*csum[p]).
//         Square per-XCD cluster mapping (12mt x 8nt) keeps wqkv slice L2-resident.
// MODE 5: final: A=[2048][2048] wob, B=[8192][2048] obT; f32 out + bias (direct).
template<int MODE>
__global__ __launch_bounds__(512, 2)
void gemm256(const ushort* __restrict__ A, const ushort* __restrict__ B,
             const ushort* __restrict__ B2, void* __restrict__ C,
             ushort* __restrict__ Kout,
             const float* __restrict__ bias0, const float* __restrict__ bias1,
             const float* __restrict__ bias2, const float* __restrict__ csum,
             int MT, int K)
{
    __shared__ __align__(16) ushort lds[4][2][8192];   // 128 KiB ring: 4 x (A,B) x 256x32

    int nwg = gridDim.x;
    int bid = blockIdx.x;
    int mt, nt;
    if (MODE == 4) {
        int xcd = bid & 7, idx = bid >> 3;     // idx 0..95 per XCD
        mt = (xcd & 1) * 12 + idx % 12;        // 0..23
        nt = (xcd >> 1) * 8 + idx / 12;        // 0..31
    } else {
        int cpx = nwg >> 3;
        int swz = (bid & 7) * cpx + (bid >> 3);
        mt = swz % MT; nt = swz / MT;
    }
    int m0 = mt << 8, n0 = nt << 8;
    int sec = m0 >> 11;                        // MODE4: 0=q, 1=k, 2=v (block-uniform)

    int tid = threadIdx.x;
    int wave = tid >> 6, lane = tid & 63;
    int wr = wave >> 2, wc = wave & 3;         // 2x4 wave grid; per-wave C = 128x64
    int l16 = lane & 15, quad = lane >> 4;

    const ushort* Bb = (MODE == 4 && sec == 1) ? B2 : B;

    int lc = (((lane & 3) ^ ((lane >> 3) & 3))) * 8;
    const ushort* gA0 = A + (long long)(m0 + wave * 16 + (lane >> 2)) * K + lc;
    const ushort* gA1 = gA0 + (long long)128 * K;
    const ushort* gB0 = Bb + (long long)(n0 + wave * 16 + (lane >> 2)) * K + lc;
    const ushort* gB1 = gB0 + (long long)128 * K;
    int ldso = wave * 512;                     // wave's 1KB stripe (ushorts)

    int rsw = ((l16 >> 1) & 3) * 8;
    int aoff = (wr * 128 + l16) * 32 + ((quad * 8) ^ rsw);
    int boff = (wc * 64 + l16) * 32 + ((quad * 8) ^ rsw);

    fx4 acc[8][4];
#pragma unroll
    for (int i = 0; i < 8; ++i)
#pragma unroll
        for (int j = 0; j < 4; ++j) acc[i][j] = (fx4){0.f, 0.f, 0.f, 0.f};

    auto stageA = [&](int b, int kc) {
        gload_lds16(gA0 + kc, &lds[b][0][ldso]);
        gload_lds16(gA1 + kc, &lds[b][0][4096 + ldso]);
    };
    auto stageB = [&](int b, int kc) {
        gload_lds16(gB0 + kc, &lds[b][1][ldso]);
        gload_lds16(gB1 + kc, &lds[b][1][4096 + ldso]);
    };

    short8 af[4], bf[4];
    auto readA = [&](int b, int half) {
        const ushort* p = &lds[b][0][aoff + half * 2048];
#pragma unroll
        for (int i = 0; i < 4; ++i) af[i] = *(const short8*)(p + i * 512);
    };
    auto readB = [&](int b) {
        const ushort* p = &lds[b][1][boff];
#pragma unroll
        for (int j = 0; j < 4; ++j) bf[j] = *(const short8*)(p + j * 512);
    };
    auto mma = [&](int half) {
        __builtin_amdgcn_s_setprio(1);
#pragma unroll
        for (int i = 0; i < 4; ++i)
#pragma unroll
            for (int j = 0; j < 4; ++j)
                acc[half * 4 + i][j] =
                    __builtin_amdgcn_mfma_f32_16x16x32_bf16(af[i], bf[j], acc[half * 4 + i][j], 0, 0, 0);
        __builtin_amdgcn_s_setprio(0);
    };

    int NT = K >> 5;
    stageA(0, 0);  stageB(0, 0);
    stageA(1, 32); stageB(1, 32);
    stageA(2, 64); stageB(2, 64);
    asm volatile("s_waitcnt vmcnt(8)" ::: "memory");
    __builtin_amdgcn_s_barrier();

    for (int t = 0; t < NT; ++t) {
        int b = t & 3;
        readA(b, 0); readB(b);
        if (t + 3 < NT) stageA((t + 3) & 3, (t + 3) << 5);
        __builtin_amdgcn_s_barrier();
        asm volatile("s_waitcnt lgkmcnt(0)" ::: "memory");
        __builtin_amdgcn_sched_barrier(0);
        mma(0);
        __builtin_amdgcn_s_barrier();
        readA(b, 1);
        if (t + 3 < NT) {
            stageB((t + 3) & 3, (t + 3) << 5);
            asm volatile("s_waitcnt vmcnt(8)" ::: "memory");
        } else if (t + 2 < NT) {
            asm volatile("s_waitcnt vmcnt(4)" ::: "memory");
        } else if (t + 1 < NT) {
            asm volatile("s_waitcnt vmcnt(0)" ::: "memory");
        }
        __builtin_amdgcn_s_barrier();
        asm volatile("s_waitcnt lgkmcnt(0)" ::: "memory");
        __builtin_amdgcn_sched_barrier(0);
        mma(1);
        __builtin_amdgcn_s_barrier();
    }

    if (MODE == 5) {
        float* Cf = (float*)C + (long long)nt * 524288;
#pragma unroll
        for (int i = 0; i < 8; ++i) {
            int m = m0 + wr * 128 + i * 16 + quad * 4;
#pragma unroll
            for (int j = 0; j < 4; ++j) {
                int n = wc * 64 + j * 16 + l16;
                float* dst = Cf + (long long)m * 256 + n;
#pragma unroll
                for (int r = 0; r < 4; ++r)
                    dst[(long)r * 256] = acc[i][j][r] + bias0[m + r];
            }
        }
        return;
    }

    if (MODE == 4) {
        int ms0 = m0 & 2047;
        ushort* ct = &lds[0][0][0];            // re-tile buffer: 128 x 264 ushorts
        if (sec < 2) {
            const float* bs = (sec == 0) ? bias0 : bias1;
            ushort* base = ((sec == 0) ? (ushort*)C : Kout)
                         + (long long)nt * 524288 + (long long)(ms0 >> 8) * 65536;
#pragma unroll
            for (int hh = 0; hh < 2; ++hh) {
                if ((wc >> 1) == hh) {
#pragma unroll
                    for (int i = 0; i < 8; ++i)
#pragma unroll
                        for (int j = 0; j < 4; ++j) {
                            int nl = (wc & 1) * 64 + j * 16 + l16;
                            int ml = wr * 128 + i * 16 + quad * 4;
                            float csf = (sec == 1) ? csum[hh * 128 + nl] : 1.0f;
                            ushort4v pk;
#pragma unroll
                            for (int r = 0; r < 4; ++r)
                                pk[r] = f2bf(acc[i][j][r] + bs[ms0 + ml + r] * csf);
                            *(ushort4v*)(ct + nl * 264 + ml) = pk;
                        }
                }
                __syncthreads();
                int row = tid & 127, c0 = (tid >> 7) * 64;
                ushort* dst = base + (long long)(hh * 128 + row) * 256 + c0;
                const ushort* src = ct + row * 264 + c0;
#pragma unroll
                for (int u = 0; u < 8; ++u)
                    *(ushort8*)(dst + u * 8) = *(const ushort8*)(src + u * 8);
                __syncthreads();
            }
        } else {
            ushort* base = (ushort*)C + 33554432LL + (long long)nt * 524288
                         + (long long)ms0 * 256;
#pragma unroll
            for (int hh = 0; hh < 2; ++hh) {
                if (wr == hh) {
#pragma unroll
                    for (int i = 0; i < 8; ++i)
#pragma unroll
                        for (int j = 0; j < 4; ++j) {
                            int nl = wc * 64 + j * 16 + l16;
                            int ml = i * 16 + quad * 4;
#pragma unroll
                            for (int r = 0; r < 4; ++r)
                                ct[(ml + r) * 264 + nl] =
                                    f2bf(acc[i][j][r] + bias2[ms0 + hh * 128 + ml + r]);
                        }
                }
                __syncthreads();
                int row = tid & 127, c0 = (tid >> 7) * 64;
                ushort* dst = base + (long long)(hh * 128 + row) * 256 + c0;
                const ushort* src = ct + row * 264 + c0;
#pragma unroll
                for (int u = 0; u < 8; ++u)
                    *(ushort8*)(dst + u * 8) = *(const ushort8*)(src + u * 8);
                __syncthreads();
            }
        }
        return;
    }
}

extern "C" void kernel_launch(void* const* d_in, const int* in_sizes, int n_in,
                              void* d_out, int out_size, void* d_ws, size_t ws_size,
                              hipStream_t stream)
{
    const float* x     = (const float*)d_in[0];
    const float* Wq    = (const float*)d_in[1];
    const float* bq    = (const float*)d_in[2];
    const float* Wk    = (const float*)d_in[3];
    const float* bk    = (const float*)d_in[4];
    const float* Wv    = (const float*)d_in[5];
    const float* bv    = (const float*)d_in[6];
    const float* Wo    = (const float*)d_in[7];
    const float* bo    = (const float*)d_in[8];
    const float* coeff = (const float*)d_in[9];
    const float* scale = (const float*)d_in[10];
    float* out = (float*)d_out;

    size_t o = 0;
    char* w = (char*)d_ws;
    auto take = [&](size_t bytes) -> void* {
        void* p = w + o; o += (bytes + 255) & ~(size_t)255; return p;
    };
    int*    coo_cnt = (int*)take(4);
    int*    coo_m   = (int*)take(MAXNNZ * 4);
    int*    coo_p   = (int*)take(MAXNNZ * 4);
    float*  coo_v   = (float*)take(MAXNNZ * 4);
    int*    csc_ptr = (int*)take(257 * 4);
    int*    csc_m   = (int*)take(MAXNNZ * 4);
    float*  csc_v   = (float*)take(MAXNNZ * 4);
    float*  csum    = (float*)take(256 * 4);
    ushort* wqkv = (ushort*)take(6144L * 512 * 2);       // [wq;wk;wv] stacked
    ushort* wob  = (ushort*)take(2048L * 2048 * 2);
    ushort* xT   = (ushort*)take(32L * 256 * 512 * 2);   // [b][n][cin] == [8192][512]
    ushort* qkv  = (ushort*)take(3 * 16777216L * 2);     // qbT | (free) | vb contiguous
    ushort* qbT = qkv;                                   // [b][h][n][d]
    ushort* mid = qkv + 16777216L;                       // xc, later obT
    ushort* vb  = qkv + 33554432L;                       // [b][2048][256]
    ushort* ktc = (ushort*)take(16777216L * 2);          // [z][p][d]
    ushort* xc  = mid;                                   // [8192][512] (8.4MB, dead after gemm4)
    ushort* obT = mid;                                   // [8192][2048] (after attn)
    (void)in_sizes; (void)n_in; (void)out_size; (void)ws_size;

    // 1) sparsity structure (+ per-column coefficient sums)
    hipMemsetAsync(coo_cnt, 0, 4, stream);
    topk_kernel<<<256, 256, 0, stream>>>(coeff, coo_cnt, coo_m, coo_p, coo_v);
    csc_kernel<<<1, 256, 0, stream>>>(coo_cnt, coo_m, coo_p, coo_v,
                                      csc_ptr, csc_m, csc_v, csum);

    // 2) weight converts + x transpose
    cvt4_kernel<<<dim3(1024, 4, 1), 256, 0, stream>>>(
        Wq, wqkv, 2048 * 512, Wk, wqkv + 2048L * 512, 2048 * 512,
        Wv, wqkv + 4096L * 512, 2048 * 512, Wo, wob, 2048 * 2048);
    transpose_f32_bf16<<<dim3(8, 4, 32), 256, 0, stream>>>(x, xT, 512, 256);

    // 3) x-combine (sparse combine moved before the K projection)
    xcomb_kernel<<<dim3(8, 32), 256, 0, stream>>>(xT, xc, csc_ptr, csc_m, csc_v);

    // 4) merged QKV projection: q,v from xT; k~ from xc -> ktc directly
    gemm256<4><<<dim3(768, 1, 1), dim3(512, 1, 1), 0, stream>>>(
        wqkv, xT, xc, qkv, ktc, bq, bk, bv, csum, 24, 512);

    // 5+6) fused attention: softmax(Q^T K~ / s) V -> obT [8192][2048]
    attn_kernel<<<512, 256, 0, stream>>>(qbT, ktc, vb, obT, scale);

    // 7) merged final projection: [2048,2048] x [8192,2048]^T -> out f32 [b][2048][256]
    gemm256<5><<<dim3(256, 1, 1), dim3(512, 1, 1), 0, stream>>>(
        wob, obT, nullptr, out, nullptr, bo, nullptr, nullptr, nullptr, 8, 2048);
}

// Round 8
// 358.932 us; speedup vs baseline: 1.1716x; 1.0148x over previous
//
#include <hip/hip_runtime.h>

typedef unsigned short ushort;
typedef __attribute__((ext_vector_type(8))) short short8;
typedef __attribute__((ext_vector_type(8))) unsigned short ushort8;
typedef __attribute__((ext_vector_type(4))) unsigned short ushort4v;
typedef __attribute__((ext_vector_type(4))) float fx4;

#define MAXNNZ (256*7)

__device__ __forceinline__ ushort f2bf(float f) {
    union { float f; unsigned u; } v; v.f = f;
    unsigned r = v.u + 0x7fffu + ((v.u >> 16) & 1u);
    return (ushort)(r >> 16);
}

__device__ __forceinline__ float bf2f(ushort b) {
    union { unsigned u; float f; } v; v.u = ((unsigned)b) << 16;
    return v.f;
}

// async global->LDS, 16B per lane; LDS dest = wave-uniform base + lane*16
__device__ __forceinline__ void gload_lds16(const ushort* g, ushort* l) {
    __builtin_amdgcn_global_load_lds(
        (const __attribute__((address_space(1))) unsigned int*)g,
        (__attribute__((address_space(3))) unsigned int*)l, 16, 0, 0);
}

// ---------------- top-7 per row of coeff (rows 0..255), emit COO for cols<256 -----
__global__ __launch_bounds__(256)
void topk_kernel(const float* __restrict__ coeff,
                 int* __restrict__ coo_cnt, int* __restrict__ coo_m,
                 int* __restrict__ coo_p, float* __restrict__ coo_v)
{
    int row = blockIdx.x;            // = m index, 0..255
    int tid = threadIdx.x;
    const float* crow = coeff + (long)row * 2048;
    float av[8];
#pragma unroll
    for (int i = 0; i < 8; ++i) av[i] = fabsf(crow[tid + 256 * i]);
    __shared__ unsigned long long red[256];
    for (int t = 0; t < 7; ++t) {
        float mx = -1.f; int mi = 0;
#pragma unroll
        for (int i = 0; i < 8; ++i) if (av[i] > mx) { mx = av[i]; mi = i; }
        unsigned col = (unsigned)(tid + 256 * mi);
        unsigned long long pk = ((unsigned long long)__float_as_uint(mx) << 32)
                              | (unsigned long long)(2048u - col); // tie -> smaller col
        red[tid] = pk; __syncthreads();
        for (int s = 128; s > 0; s >>= 1) {
            if (tid < s) { if (red[tid + s] > red[tid]) red[tid] = red[tid + s]; }
            __syncthreads();
        }
        unsigned long long w = red[0];
        __syncthreads();
        unsigned wcol = 2048u - (unsigned)(w & 0xffffffffu);
        if ((wcol & 255u) == (unsigned)tid) av[wcol >> 8] = -1.f; // consume
        if (tid == 0 && wcol < 256u) {
            int pos = atomicAdd(coo_cnt, 1);
            coo_m[pos] = row; coo_p[pos] = (int)wcol; coo_v[pos] = crow[wcol];
        }
    }
}

// ---------------- COO -> CSC (single block) + per-column value sums ----------------
__global__ __launch_bounds__(256)
void csc_kernel(const int* __restrict__ coo_cnt, const int* __restrict__ coo_m,
                const int* __restrict__ coo_p, const float* __restrict__ coo_v,
                int* __restrict__ csc_ptr, int* __restrict__ csc_m,
                float* __restrict__ csc_v, float* __restrict__ csum)
{
    __shared__ int cnt[256];
    __shared__ int off[257];
    __shared__ int cur[256];
    int tid = threadIdx.x;
    cnt[tid] = 0;
    __syncthreads();
    int n = *coo_cnt; if (n > MAXNNZ) n = MAXNNZ;
    for (int e = tid; e < n; e += 256) atomicAdd(&cnt[coo_p[e]], 1);
    __syncthreads();
    if (tid == 0) {
        int s = 0;
        for (int p = 0; p < 256; ++p) { off[p] = s; s += cnt[p]; }
        off[256] = s;
    }
    __syncthreads();
    csc_ptr[tid] = off[tid];
    if (tid == 0) csc_ptr[256] = off[256];
    cur[tid] = off[tid];
    __syncthreads();
    for (int e = tid; e < n; e += 256) {
        int p = coo_p[e];
        int pos = atomicAdd(&cur[p], 1);
        csc_m[pos] = coo_m[e];
        csc_v[pos] = coo_v[e];
    }
    __syncthreads();
    {   // column value-sum (for bias scaling of combined-K path)
        float s = 0.f;
        int e0 = off[tid], e1 = off[tid] + cnt[tid];
        for (int e = e0; e < e1; ++e) s += csc_v[e];
        csum[tid] = s;
    }
}

// ---------------- fp32 -> bf16 convert, 4 tensors in one launch ----------------
__global__ void cvt4_kernel(const float* a0, ushort* d0, int n0,
                            const float* a1, ushort* d1, int n1,
                            const float* a2, ushort* d2, int n2,
                            const float* a3, ushort* d3, int n3)
{
    const float* s; ushort* d; int n;
    switch (blockIdx.y) {
        case 0: s = a0; d = d0; n = n0; break;
        case 1: s = a1; d = d1; n = n1; break;
        case 2: s = a2; d = d2; n = n2; break;
        default: s = a3; d = d3; n = n3; break;
    }
    int nv = n >> 2;
    for (int i = blockIdx.x * blockDim.x + threadIdx.x; i < nv; i += gridDim.x * blockDim.x) {
        fx4 v = ((const fx4*)s)[i];
        ushort4v o;
        o[0] = f2bf(v[0]); o[1] = f2bf(v[1]); o[2] = f2bf(v[2]); o[3] = f2bf(v[3]);
        ((ushort4v*)d)[i] = o;
    }
}

// ---------------- transpose f32 [z][R][C] -> bf16 [z][C][R] ----------------
__global__ __launch_bounds__(256)
void transpose_f32_bf16(const float* __restrict__ in, ushort* __restrict__ out, int R, int C)
{
    int z = blockIdx.z;
    const float* ib = in + (long)z * R * C;
    ushort* ob = out + (long)z * R * C;
    __shared__ ushort tile[64][72];
    int r0 = blockIdx.x * 64, c0 = blockIdx.y * 64;
    int tid = threadIdx.x;
    int rl = tid >> 2, sg = tid & 3;
#pragma unroll
    for (int h = 0; h < 4; ++h) {
        fx4 v = *(const fx4*)(ib + (long)(r0 + rl) * C + c0 + h * 16 + sg * 4);
#pragma unroll
        for (int i = 0; i < 4; ++i) tile[h * 16 + sg * 4 + i][rl] = f2bf(v[i]);
    }
    __syncthreads();
    int cl = rl;
#pragma unroll
    for (int h = 0; h < 2; ++h) {
        ushort8 vv = *(const ushort8*)(&tile[cl][h * 32 + sg * 8]);
        *(ushort8*)(ob + (long)(c0 + cl) * R + r0 + h * 32 + sg * 8) = vv;
    }
}

// ---------------- x-combine: xc[b][p][c] = sum_e csc_v[e] * xT[b][m_e][c] ----------
// (sparse combine commuted before the K-projection: K~ = (C^T X) Wk^T)
__global__ __launch_bounds__(256)
void xcomb_kernel(const ushort* __restrict__ xT, ushort* __restrict__ xc,
                  const int* __restrict__ csc_ptr, const int* __restrict__ csc_m,
                  const float* __restrict__ csc_v)
{
    int b = blockIdx.y;
    int tid = threadIdx.x;
    int p = blockIdx.x * 32 + (tid >> 3);
    int c0 = (tid & 7) * 64;
    const ushort* src = xT + (long)b * 131072;      // 256 x 512
    float acc[64];
#pragma unroll
    for (int i = 0; i < 64; ++i) acc[i] = 0.f;
    int e0 = csc_ptr[p], e1 = csc_ptr[p + 1];
    for (int e = e0; e < e1; ++e) {
        const ushort* row = src + csc_m[e] * 512 + c0;
        float c = csc_v[e];
#pragma unroll
        for (int u = 0; u < 8; ++u) {
            ushort8 v = *(const ushort8*)(row + u * 8);
#pragma unroll
            for (int t = 0; t < 8; ++t) acc[u * 8 + t] += bf2f(v[t]) * c;
        }
    }
    ushort* dst = xc + (long)b * 131072 + (long)p * 512 + c0;
#pragma unroll
    for (int u = 0; u < 8; ++u) {
        ushort8 o;
#pragma unroll
        for (int t = 0; t < 8; ++t) o[t] = f2bf(acc[u * 8 + t]);
        *(ushort8*)(dst + u * 8) = o;
    }
}

// ---------------- fused attention v4: T=QK~^T/s, softmax, O = P V^T ----------------
// Block = (z, n-half): 512 blocks x 256 threads (4 waves), LDS ~70KB -> 2 blocks/CU.
// Q staged once into LDS (PQ, reused as P then O-retile). K~ and V are stored
// FRAGMENT-MAJOR by the producer ([kchunk][256 lanes][8]): each fragment load is a
// fully-coalesced 16B/lane stream (base + chunk*2048 + lane*8). 1-deep prefetch.
__global__ __launch_bounds__(256, 2)
void attn_kernel(const ushort* __restrict__ Q, const ushort* __restrict__ Kt,
                 const ushort* __restrict__ V, ushort* __restrict__ O,
                 const float* __restrict__ scale_src)
{
    __shared__ __align__(16) ushort PQ[32768];      // 64 KB: Q-half -> P -> O retile
    __shared__ float rmax[4][128];
    __shared__ float rsum[4][128];

    int bid = blockIdx.x;
    int hf = bid >> 8, z = bid & 255;               // (z,0),(z,1) same XCD (z%8)
    int b = z >> 3, h = z & 7;
    const ushort* Qz = Q + (long)z * 65536 + (long)hf * 32768;   // [128 n][256 d]
    const ushort* Kz = Kt + (long)z * 65536;                     // frag-major [32][256][8]
    const ushort* Vz = V + (long)b * 524288 + (long)h * 65536;   // frag-major [32][256][8]
    ushort* Ob = O + (long)b * 524288 + (long)h * 256 + (long)hf * 128 * 2048;

    int tid = threadIdx.x;
    int wave = tid >> 6, lane = tid & 63;           // wave = p/d quarter (0..3)
    int l16 = lane & 15, quad = lane >> 4;
    int key = l16 & 7;

    // ---- stage Q half [128][256] into PQ, swizzled via pre-swizzled source ----
    {
        int rb = wave * 2 + (lane >> 5);            // row base (g adds multiples of 8)
        const ushort* qsrc = Qz + (long)rb * 256 + (((lane & 31) ^ (rb & 7)) * 8);
        ushort* qdst = PQ + wave * 512;
#pragma unroll
        for (int g = 0; g < 16; ++g)
            gload_lds16(qsrc + g * 2048, qdst + g * 2048);
    }

    // fragment-major pointers: lane index lrow (p for K, d for V), chunk = quad
    int lrow = wave * 64 + l16;
    const ushort* kfp = Kz + quad * 2048 + (long)lrow * 8;
    const ushort* vfp = Vz + quad * 2048 + (long)lrow * 8;

    fx4 acc[8][4];
#pragma unroll
    for (int i = 0; i < 8; ++i)
#pragma unroll
        for (int j = 0; j < 4; ++j) acc[i][j] = (fx4){0.f, 0.f, 0.f, 0.f};

    short8 bfn[4];
#pragma unroll
    for (int j = 0; j < 4; ++j) bfn[j] = *(const short8*)(kfp + j * 128);

    __syncthreads();                                 // Q staged (+ bf0 ready)

    float sc = 1.0f / scale_src[0];

    // ---- phase 1: S[128 n][64 p(wave)] = Q K~^T, k = d (8 steps of 32) ----
#pragma unroll
    for (int kd = 0; kd < 8; ++kd) {
        short8 bf[4];
#pragma unroll
        for (int j = 0; j < 4; ++j) bf[j] = bfn[j];
        if (kd < 7) {
#pragma unroll
            for (int j = 0; j < 4; ++j)
                bfn[j] = *(const short8*)(kfp + (kd + 1) * 8192 + j * 128);
        }
        short8 af[8];
#pragma unroll
        for (int i = 0; i < 8; ++i)
            af[i] = *(const short8*)(PQ + (i * 16 + l16) * 256 + (((kd * 4 + quad) ^ key) * 8));
        __builtin_amdgcn_s_setprio(1);
#pragma unroll
        for (int i = 0; i < 8; ++i)
#pragma unroll
            for (int j = 0; j < 4; ++j)
                acc[i][j] = __builtin_amdgcn_mfma_f32_16x16x32_bf16(af[i], bf[j], acc[i][j], 0, 0, 0);
        __builtin_amdgcn_s_setprio(0);
    }

    // ---- softmax over p (rows n) ----
#pragma unroll
    for (int i = 0; i < 8; ++i)
#pragma unroll
        for (int j = 0; j < 4; ++j)
#pragma unroll
            for (int r = 0; r < 4; ++r) acc[i][j][r] *= sc;

    float lm[8][4];
#pragma unroll
    for (int i = 0; i < 8; ++i)
#pragma unroll
        for (int r = 0; r < 4; ++r) {
            float m = -1e30f;
#pragma unroll
            for (int j = 0; j < 4; ++j) m = fmaxf(m, acc[i][j][r]);
            lm[i][r] = m;
        }
#pragma unroll
    for (int d = 1; d < 16; d <<= 1)
#pragma unroll
        for (int i = 0; i < 8; ++i)
#pragma unroll
            for (int r = 0; r < 4; ++r) lm[i][r] = fmaxf(lm[i][r], __shfl_xor(lm[i][r], d, 16));
    if (l16 == 0) {
#pragma unroll
        for (int i = 0; i < 8; ++i)
#pragma unroll
            for (int r = 0; r < 4; ++r)
                rmax[wave][i * 16 + quad * 4 + r] = lm[i][r];
    }
    __syncthreads();

    float ls[8][4];
#pragma unroll
    for (int i = 0; i < 8; ++i)
#pragma unroll
        for (int r = 0; r < 4; ++r) {
            int row = i * 16 + quad * 4 + r;
            float M = fmaxf(fmaxf(rmax[0][row], rmax[1][row]),
                            fmaxf(rmax[2][row], rmax[3][row]));
            float s = 0.f;
#pragma unroll
            for (int j = 0; j < 4; ++j) {
                float e = __expf(acc[i][j][r] - M);
                acc[i][j][r] = e;
                s += e;
            }
            ls[i][r] = s;
        }
#pragma unroll
    for (int d = 1; d < 16; d <<= 1)
#pragma unroll
        for (int i = 0; i < 8; ++i)
#pragma unroll
            for (int r = 0; r < 4; ++r) ls[i][r] += __shfl_xor(ls[i][r], d, 16);
    if (l16 == 0) {
#pragma unroll
        for (int i = 0; i < 8; ++i)
#pragma unroll
            for (int r = 0; r < 4; ++r)
                rsum[wave][i * 16 + quad * 4 + r] = ls[i][r];
    }
    __syncthreads();

    short8 vfn[4];
#pragma unroll
    for (int j = 0; j < 4; ++j) vfn[j] = *(const short8*)(vfp + j * 128);

    // normalize + write P into PQ (Q dead), swizzled chunk ^= row&7
#pragma unroll
    for (int i = 0; i < 8; ++i)
#pragma unroll
        for (int r = 0; r < 4; ++r) {
            int row = i * 16 + quad * 4 + r;
            float inv = 1.0f / (rsum[0][row] + rsum[1][row] + rsum[2][row] + rsum[3][row]);
            int k2 = row & 7;
#pragma unroll
            for (int j = 0; j < 4; ++j) {
                int p = wave * 64 + j * 16 + l16;
                PQ[row * 256 + ((((p >> 3) ^ k2) << 3) | (p & 7))] = f2bf(acc[i][j][r] * inv);
            }
        }
    __syncthreads();

    // ---- phase 2: O[128 n][64 d(wave)] = P V^T, k = p (8 steps of 32) ----
    fx4 acc2[8][4];
#pragma unroll
    for (int i = 0; i < 8; ++i)
#pragma unroll
        for (int j = 0; j < 4; ++j) acc2[i][j] = (fx4){0.f, 0.f, 0.f, 0.f};

#pragma unroll
    for (int kp = 0; kp < 8; ++kp) {
        short8 vf[4];
#pragma unroll
        for (int j = 0; j < 4; ++j) vf[j] = vfn[j];
        if (kp < 7) {
#pragma unroll
            for (int j = 0; j < 4; ++j)
                vfn[j] = *(const short8*)(vfp + (kp + 1) * 8192 + j * 128);
        }
        short8 pa[8];
#pragma unroll
        for (int i = 0; i < 8; ++i)
            pa[i] = *(const short8*)(PQ + (i * 16 + l16) * 256 + (((kp * 4 + quad) ^ key) * 8));
        __builtin_amdgcn_s_setprio(1);
#pragma unroll
        for (int i = 0; i < 8; ++i)
#pragma unroll
            for (int j = 0; j < 4; ++j)
                acc2[i][j] = __builtin_amdgcn_mfma_f32_16x16x32_bf16(pa[i], vf[j], acc2[i][j], 0, 0, 0);
        __builtin_amdgcn_s_setprio(0);
    }

    // ---- epilogue: retile O through PQ (dead), coalesced 512B-row stores ----
    __syncthreads();                                // all waves done reading P
#pragma unroll
    for (int i = 0; i < 8; ++i)
#pragma unroll
        for (int j = 0; j < 4; ++j) {
            int rowb = i * 16 + quad * 4;
            int col = wave * 64 + j * 16 + l16;
#pragma unroll
            for (int rr = 0; rr < 4; ++rr) {
                int row = rowb + rr;
                PQ[row * 256 + ((((col >> 3) ^ (row & 7)) << 3) | (col & 7))]
                    = f2bf(acc2[i][j][rr]);
            }
        }
    __syncthreads();
#pragma unroll
    for (int pass = 0; pass < 16; ++pass) {
        int row = pass * 8 + (tid >> 5), ch = tid & 31;
        ushort8 vv = *(const ushort8*)(PQ + row * 256 + ((ch ^ (row & 7)) << 3));
        *(ushort8*)(Ob + (long)row * 2048 + ch * 8) = vv;
    }
}

// ---------------- 256x256-tile NT GEMM, 8 waves, fine-phase pipelined --------------
// 4-deep LDS ring (BK=32), 2 phases per K-tile; counted vmcnt; swizzled LDS.
// MODE 4: merged QKV, A=[6144][512] wqkv; B = xT for q/v sections, B2 = xc for the
//         k section. q -> [b][h][n][d]; k~ -> Kout FRAGMENT-MAJOR [z][d>>3][p][8]
//         (bias bk[d]*csum[p]); v -> FRAGMENT-MAJOR [b][h][p>>3][d][8].
//         Square per-XCD cluster mapping (12mt x 8nt) keeps wqkv slice L2-resident.
// MODE 5: final: A=[2048][2048] wob, B=[8192][2048] obT; f32 out + bias (direct).
template<int MODE>
__global__ __launch_bounds__(512, 2)
void gemm256(const ushort* __restrict__ A, const ushort* __restrict__ B,
             const ushort* __restrict__ B2, void* __restrict__ C,
             ushort* __restrict__ Kout,
             const float* __restrict__ bias0, const float* __restrict__ bias1,
             const float* __restrict__ bias2, const float* __restrict__ csum,
             int MT, int K)
{
    __shared__ __align__(16) ushort lds[4][2][8192];   // 128 KiB ring: 4 x (A,B) x 256x32

    int nwg = gridDim.x;
    int bid = blockIdx.x;
    int mt, nt;
    if (MODE == 4) {
        int xcd = bid & 7, idx = bid >> 3;     // idx 0..95 per XCD
        mt = (xcd & 1) * 12 + idx % 12;        // 0..23
        nt = (xcd >> 1) * 8 + idx / 12;        // 0..31
    } else {
        int cpx = nwg >> 3;
        int swz = (bid & 7) * cpx + (bid >> 3);
        mt = swz % MT; nt = swz / MT;
    }
    int m0 = mt << 8, n0 = nt << 8;
    int sec = m0 >> 11;                        // MODE4: 0=q, 1=k, 2=v (block-uniform)

    int tid = threadIdx.x;
    int wave = tid >> 6, lane = tid & 63;
    int wr = wave >> 2, wc = wave & 3;         // 2x4 wave grid; per-wave C = 128x64
    int l16 = lane & 15, quad = lane >> 4;

    const ushort* Bb = (MODE == 4 && sec == 1) ? B2 : B;

    int lc = (((lane & 3) ^ ((lane >> 3) & 3))) * 8;
    const ushort* gA0 = A + (long long)(m0 + wave * 16 + (lane >> 2)) * K + lc;
    const ushort* gA1 = gA0 + (long long)128 * K;
    const ushort* gB0 = Bb + (long long)(n0 + wave * 16 + (lane >> 2)) * K + lc;
    const ushort* gB1 = gB0 + (long long)128 * K;
    int ldso = wave * 512;                     // wave's 1KB stripe (ushorts)

    int rsw = ((l16 >> 1) & 3) * 8;
    int aoff = (wr * 128 + l16) * 32 + ((quad * 8) ^ rsw);
    int boff = (wc * 64 + l16) * 32 + ((quad * 8) ^ rsw);

    fx4 acc[8][4];
#pragma unroll
    for (int i = 0; i < 8; ++i)
#pragma unroll
        for (int j = 0; j < 4; ++j) acc[i][j] = (fx4){0.f, 0.f, 0.f, 0.f};

    auto stageA = [&](int b, int kc) {
        gload_lds16(gA0 + kc, &lds[b][0][ldso]);
        gload_lds16(gA1 + kc, &lds[b][0][4096 + ldso]);
    };
    auto stageB = [&](int b, int kc) {
        gload_lds16(gB0 + kc, &lds[b][1][ldso]);
        gload_lds16(gB1 + kc, &lds[b][1][4096 + ldso]);
    };

    short8 af[4], bf[4];
    auto readA = [&](int b, int half) {
        const ushort* p = &lds[b][0][aoff + half * 2048];
#pragma unroll
        for (int i = 0; i < 4; ++i) af[i] = *(const short8*)(p + i * 512);
    };
    auto readB = [&](int b) {
        const ushort* p = &lds[b][1][boff];
#pragma unroll
        for (int j = 0; j < 4; ++j) bf[j] = *(const short8*)(p + j * 512);
    };
    auto mma = [&](int half) {
        __builtin_amdgcn_s_setprio(1);
#pragma unroll
        for (int i = 0; i < 4; ++i)
#pragma unroll
            for (int j = 0; j < 4; ++j)
                acc[half * 4 + i][j] =
                    __builtin_amdgcn_mfma_f32_16x16x32_bf16(af[i], bf[j], acc[half * 4 + i][j], 0, 0, 0);
        __builtin_amdgcn_s_setprio(0);
    };

    int NT = K >> 5;
    stageA(0, 0);  stageB(0, 0);
    stageA(1, 32); stageB(1, 32);
    stageA(2, 64); stageB(2, 64);
    asm volatile("s_waitcnt vmcnt(8)" ::: "memory");
    __builtin_amdgcn_s_barrier();

    for (int t = 0; t < NT; ++t) {
        int b = t & 3;
        readA(b, 0); readB(b);
        if (t + 3 < NT) stageA((t + 3) & 3, (t + 3) << 5);
        __builtin_amdgcn_s_barrier();
        asm volatile("s_waitcnt lgkmcnt(0)" ::: "memory");
        __builtin_amdgcn_sched_barrier(0);
        mma(0);
        __builtin_amdgcn_s_barrier();
        readA(b, 1);
        if (t + 3 < NT) {
            stageB((t + 3) & 3, (t + 3) << 5);
            asm volatile("s_waitcnt vmcnt(8)" ::: "memory");
        } else if (t + 2 < NT) {
            asm volatile("s_waitcnt vmcnt(4)" ::: "memory");
        } else if (t + 1 < NT) {
            asm volatile("s_waitcnt vmcnt(0)" ::: "memory");
        }
        __builtin_amdgcn_s_barrier();
        asm volatile("s_waitcnt lgkmcnt(0)" ::: "memory");
        __builtin_amdgcn_sched_barrier(0);
        mma(1);
        __builtin_amdgcn_s_barrier();
    }

    if (MODE == 5) {
        float* Cf = (float*)C + (long long)nt * 524288;
#pragma unroll
        for (int i = 0; i < 8; ++i) {
            int m = m0 + wr * 128 + i * 16 + quad * 4;
#pragma unroll
            for (int j = 0; j < 4; ++j) {
                int n = wc * 64 + j * 16 + l16;
                float* dst = Cf + (long long)m * 256 + n;
#pragma unroll
                for (int r = 0; r < 4; ++r)
                    dst[(long)r * 256] = acc[i][j][r] + bias0[m + r];
            }
        }
        return;
    }

    if (MODE == 4) {
        int ms0 = m0 & 2047;
        ushort* ct = &lds[0][0][0];            // re-tile buffer: 128 x 264 ushorts
        if (sec < 2) {
            const float* bs = (sec == 0) ? bias0 : bias1;
            ushort* base;
            if (sec == 0)
                base = (ushort*)C + (long long)nt * 524288 + (long long)(ms0 >> 8) * 65536;
            else
                base = Kout + (long long)(nt * 8 + (ms0 >> 8)) * 65536;  // frag-major z
#pragma unroll
            for (int hh = 0; hh < 2; ++hh) {   // p-halves; waves wc>>1==hh own half
                if ((wc >> 1) == hh) {
#pragma unroll
                    for (int i = 0; i < 8; ++i)
#pragma unroll
                        for (int j = 0; j < 4; ++j) {
                            int nl = (wc & 1) * 64 + j * 16 + l16;
                            int ml = wr * 128 + i * 16 + quad * 4;
                            float csf = (sec == 1) ? csum[hh * 128 + nl] : 1.0f;
                            ushort4v pk;
#pragma unroll
                            for (int r = 0; r < 4; ++r)
                                pk[r] = f2bf(acc[i][j][r] + bs[ms0 + ml + r] * csf);
                            *(ushort4v*)(ct + nl * 264 + ml) = pk;
                        }
                }
                __syncthreads();
                int row = tid & 127, c0 = (tid >> 7) * 64;
                const ushort* src = ct + row * 264 + c0;
                if (sec == 0) {
                    ushort* dst = base + (long long)(hh * 128 + row) * 256 + c0;
#pragma unroll
                    for (int u = 0; u < 8; ++u)
                        *(ushort8*)(dst + u * 8) = *(const ushort8*)(src + u * 8);
                } else {
                    // frag-major: dst = z-base + (d>>3)*2048 + p*8  (p = hh*128+row)
                    ushort* pdst = base + (long long)(hh * 128 + row) * 8;
#pragma unroll
                    for (int u = 0; u < 8; ++u)
                        *(ushort8*)(pdst + (long long)((c0 >> 3) + u) * 2048)
                            = *(const ushort8*)(src + u * 8);
                }
                __syncthreads();
            }
        } else {
            // v section: frag-major [b][h][p>>3][d][8]
            ushort* vbase = (ushort*)C + 33554432LL + (long long)nt * 524288
                          + (long long)(ms0 >> 8) * 65536;
#pragma unroll
            for (int hh = 0; hh < 2; ++hh) {   // d-halves; waves wr==hh own half
                if (wr == hh) {
#pragma unroll
                    for (int i = 0; i < 8; ++i)
#pragma unroll
                        for (int j = 0; j < 4; ++j) {
                            int nl = wc * 64 + j * 16 + l16;
                            int ml = i * 16 + quad * 4;
#pragma unroll
                            for (int r = 0; r < 4; ++r)
                                ct[(ml + r) * 264 + nl] =
                                    f2bf(acc[i][j][r] + bias2[ms0 + hh * 128 + ml + r]);
                        }
                }
                __syncthreads();
                int row = tid & 127, c0 = (tid >> 7) * 64;
                const ushort* src = ct + row * 264 + c0;
                // dst = v-base + (p>>3)*2048 + d*8  (d = hh*128+row)
                ushort* pdst = vbase + (long long)(hh * 128 + row) * 8;
#pragma unroll
                for (int u = 0; u < 8; ++u)
                    *(ushort8*)(pdst + (long long)((c0 >> 3) + u) * 2048)
                        = *(const ushort8*)(src + u * 8);
                __syncthreads();
            }
        }
        return;
    }
}

extern "C" void kernel_launch(void* const* d_in, const int* in_sizes, int n_in,
                              void* d_out, int out_size, void* d_ws, size_t ws_size,
                              hipStream_t stream)
{
    const float* x     = (const float*)d_in[0];
    const float* Wq    = (const float*)d_in[1];
    const float* bq    = (const float*)d_in[2];
    const float* Wk    = (const float*)d_in[3];
    const float* bk    = (const float*)d_in[4];
    const float* Wv    = (const float*)d_in[5];
    const float* bv    = (const float*)d_in[6];
    const float* Wo    = (const float*)d_in[7];
    const float* bo    = (const float*)d_in[8];
    const float* coeff = (const float*)d_in[9];
    const float* scale = (const float*)d_in[10];
    float* out = (float*)d_out;

    size_t o = 0;
    char* w = (char*)d_ws;
    auto take = [&](size_t bytes) -> void* {
        void* p = w + o; o += (bytes + 255) & ~(size_t)255; return p;
    };
    int*    coo_cnt = (int*)take(4);
    int*    coo_m   = (int*)take(MAXNNZ * 4);
    int*    coo_p   = (int*)take(MAXNNZ * 4);
    float*  coo_v   = (float*)take(MAXNNZ * 4);
    int*    csc_ptr = (int*)take(257 * 4);
    int*    csc_m   = (int*)take(MAXNNZ * 4);
    float*  csc_v   = (float*)take(MAXNNZ * 4);
    float*  csum    = (float*)take(256 * 4);
    ushort* wqkv = (ushort*)take(6144L * 512 * 2);       // [wq;wk;wv] stacked
    ushort* wob  = (ushort*)take(2048L * 2048 * 2);
    ushort* xT   = (ushort*)take(32L * 256 * 512 * 2);   // [b][n][cin] == [8192][512]
    ushort* qkv  = (ushort*)take(3 * 16777216L * 2);     // qbT | (free) | vb contiguous
    ushort* qbT = qkv;                                   // [b][h][n][d]
    ushort* mid = qkv + 16777216L;                       // xc, later obT
    ushort* vb  = qkv + 33554432L;                       // frag-major V
    ushort* ktc = (ushort*)take(16777216L * 2);          // frag-major K~
    ushort* xc  = mid;                                   // [8192][512] (dead after gemm4)
    ushort* obT = mid;                                   // [8192][2048] (after attn)
    (void)in_sizes; (void)n_in; (void)out_size; (void)ws_size;

    // 1) sparsity structure (+ per-column coefficient sums)
    hipMemsetAsync(coo_cnt, 0, 4, stream);
    topk_kernel<<<256, 256, 0, stream>>>(coeff, coo_cnt, coo_m, coo_p, coo_v);
    csc_kernel<<<1, 256, 0, stream>>>(coo_cnt, coo_m, coo_p, coo_v,
                                      csc_ptr, csc_m, csc_v, csum);

    // 2) weight converts + x transpose
    cvt4_kernel<<<dim3(1024, 4, 1), 256, 0, stream>>>(
        Wq, wqkv, 2048 * 512, Wk, wqkv + 2048L * 512, 2048 * 512,
        Wv, wqkv + 4096L * 512, 2048 * 512, Wo, wob, 2048 * 2048);
    transpose_f32_bf16<<<dim3(8, 4, 32), 256, 0, stream>>>(x, xT, 512, 256);

    // 3) x-combine (sparse combine moved before the K projection)
    xcomb_kernel<<<dim3(8, 32), 256, 0, stream>>>(xT, xc, csc_ptr, csc_m, csc_v);

    // 4) merged QKV projection: q,v from xT; k~ from xc -> ktc (frag-major)
    gemm256<4><<<dim3(768, 1, 1), dim3(512, 1, 1), 0, stream>>>(
        wqkv, xT, xc, qkv, ktc, bq, bk, bv, csum, 24, 512);

    // 5+6) fused attention: softmax(Q^T K~ / s) V -> obT [8192][2048]
    attn_kernel<<<512, 256, 0, stream>>>(qbT, ktc, vb, obT, scale);

    // 7) merged final projection: [2048,2048] x [8192,2048]^T -> out f32 [b][2048][256]
    gemm256<5><<<dim3(256, 1, 1), dim3(512, 1, 1), 0, stream>>>(
        wob, obT, nullptr, out, nullptr, bo, nullptr, nullptr, nullptr, 8, 2048);
}